// Round 15
// baseline (283.362 us; speedup 1.0000x reference)
//
#include <hip/hip_runtime.h>

typedef __bf16 bf16;
typedef __bf16 bf16x8 __attribute__((ext_vector_type(8)));
typedef __bf16 bf16x4 __attribute__((ext_vector_type(4)));
typedef float f32x4 __attribute__((ext_vector_type(4)));

__device__ __forceinline__ void gload_lds16(const void* g, void* l) {
  __builtin_amdgcn_global_load_lds(
      (const __attribute__((address_space(1))) void*)g,
      (__attribute__((address_space(3))) void*)l, 16, 0, 0);
}

__device__ __forceinline__ bf16x8 ld8(const bf16* p) {
  bf16x8 v; __builtin_memcpy(&v, p, 16); return v;
}

// ---------------- cast x (fp32 -> bf16), 8 elems/thread ----------------
__global__ __launch_bounds__(256) void cast_f32_bf16(const float* __restrict__ in,
                                                     bf16* __restrict__ out, int n8) {
  int i = blockIdx.x * 256 + threadIdx.x;
  if (i >= n8) return;
  const float4* p = (const float4*)in + (size_t)i * 2;
  float4 a = p[0], b = p[1];
  bf16x8 o;
  o[0] = (bf16)a.x; o[1] = (bf16)a.y; o[2] = (bf16)a.z; o[3] = (bf16)a.w;
  o[4] = (bf16)b.x; o[5] = (bf16)b.y; o[6] = (bf16)b.z; o[7] = (bf16)b.w;
  *((bf16x8*)out + i) = o;
}

// ---------------- transpose W (fp32 [K][N]) -> Wt (bf16 [N][K]) ----------------
__global__ __launch_bounds__(256) void transpose_w(const float* __restrict__ W,
                                                   bf16* __restrict__ Wt) {
  __shared__ bf16 tile[64][72];
  int t = threadIdx.x;
  int k0 = blockIdx.x * 64, n0 = blockIdx.y * 64;
  int r = t >> 2, c0 = (t & 3) * 16;
  const float* src = W + (size_t)(k0 + r) * 1536 + n0 + c0;
#pragma unroll
  for (int q = 0; q < 4; ++q) {
    float4 v = *(const float4*)(src + q * 4);
    tile[c0 + q * 4 + 0][r] = (bf16)v.x;
    tile[c0 + q * 4 + 1][r] = (bf16)v.y;
    tile[c0 + q * 4 + 2][r] = (bf16)v.z;
    tile[c0 + q * 4 + 3][r] = (bf16)v.w;
  }
  __syncthreads();
  bf16* dst = Wt + (size_t)(n0 + r) * 1536 + k0 + c0;
  bf16x8 o0, o1;
#pragma unroll
  for (int j = 0; j < 8; ++j) { o0[j] = tile[r][c0 + j]; o1[j] = tile[r][c0 + 8 + j]; }
  *(bf16x8*)dst = o0;
  *(bf16x8*)(dst + 8) = o1;
}

__global__ void concat_bias(const float* __restrict__ bq, const float* __restrict__ bk,
                            const float* __restrict__ bv, float* __restrict__ o) {
  int t = blockIdx.x * 256 + threadIdx.x;
  if (t < 1536) o[t] = bq[t];
  else if (t < 3072) o[t] = bk[t - 1536];
  else if (t < 4608) o[t] = bv[t - 3072];
}

// ---------------- m97-structure GEMM with XCD-locality remap ----------------
template <typename OUT>
__global__ __launch_bounds__(256, 2) void gemm_bt(const bf16* __restrict__ A, const bf16* __restrict__ B,
                                                  const float* __restrict__ bias, OUT* __restrict__ C,
                                                  int M, int N, int K, int gx) {
  __shared__ bf16 As[128 * 32], Bs[128 * 32];
  int t = threadIdx.x, l = t & 63, w = t >> 6;
  int lane15 = l & 15, lhi = l >> 4;
  int b = blockIdx.x;
  int xcd = b & 7, idx = b >> 3;
  int g = xcd * ((int)gridDim.x >> 3) + idx;
  int m0 = (g % gx) * 128, n0 = (g / gx) * 128;
  int wm = (w >> 1) * 64, wn = (w & 1) * 64;
  f32x4 zero = {0.f, 0.f, 0.f, 0.f};
  f32x4 acc[4][4];
#pragma unroll
  for (int i = 0; i < 4; ++i)
#pragma unroll
    for (int j = 0; j < 4; ++j) acc[i][j] = zero;

  int srow = t >> 2, scol = (t & 3) * 8;
  const bf16* gA0 = A + (size_t)(m0 + srow) * K + scol;
  const bf16* gA1 = A + (size_t)(m0 + 64 + srow) * K + scol;
  const bf16* gB0 = B + (size_t)(n0 + srow) * K + scol;
  const bf16* gB1 = B + (size_t)(n0 + 64 + srow) * K + scol;
  char* ldsA = (char*)As + (size_t)w * 1024;
  char* ldsB = (char*)Bs + (size_t)w * 1024;

  for (int kt = 0; kt < K; kt += 32) {
    gload_lds16(gA0 + kt, ldsA);
    gload_lds16(gA1 + kt, ldsA + 4096);
    gload_lds16(gB0 + kt, ldsB);
    gload_lds16(gB1 + kt, ldsB + 4096);
    __syncthreads();
    bf16x8 af[4], bfr[4];
#pragma unroll
    for (int i = 0; i < 4; ++i) {
      af[i]  = ld8(&As[(wm + i * 16 + lane15) * 32 + lhi * 8]);
      bfr[i] = ld8(&Bs[(wn + i * 16 + lane15) * 32 + lhi * 8]);
    }
#pragma unroll
    for (int i = 0; i < 4; ++i)
#pragma unroll
      for (int j = 0; j < 4; ++j)
        acc[i][j] = __builtin_amdgcn_mfma_f32_16x16x32_bf16(af[i], bfr[j], acc[i][j], 0, 0, 0);
    __syncthreads();
  }
#pragma unroll
  for (int i = 0; i < 4; ++i)
#pragma unroll
    for (int j = 0; j < 4; ++j) {
      int col = n0 + wn + j * 16 + lane15;
      float bb = bias[col];
#pragma unroll
      for (int r = 0; r < 4; ++r) {
        int row = m0 + wm + i * 16 + lhi * 4 + r;
        C[(size_t)row * N + col] = (OUT)(acc[i][j][r] + bb);
      }
    }
}

// ---------------- RoPE cos/sin table [3584][64] ----------------
__global__ void rope_tab(const float* __restrict__ freqs, const int* __restrict__ gs,
                         float* __restrict__ tabc, float* __restrict__ tabs) {
  int idx = blockIdx.x * 256 + threadIdx.x;
  if (idx >= 3584 * 64) return;
  int s = idx >> 6, i = idx & 63;
  int H = gs[1], W = gs[2];
  int f = s / (H * W);
  int rem = s - f * (H * W);
  int hh = rem / W;
  int ww = rem - hh * W;
  int row = (i < 22) ? f : ((i < 43) ? hh : ww);
  float a = freqs[row * 64 + i];
  tabc[idx] = cosf(a);
  tabs[idx] = sinf(a);
}

// ---------------- RMSNorm + RoPE for Q,K (e-domain, Q pre-scaled) ----------------
__global__ __launch_bounds__(256) void postproc(const bf16* __restrict__ QKV,
    const float* __restrict__ gq, const float* __restrict__ gk,
    const float* __restrict__ tabc, const float* __restrict__ tabs,
    bf16* __restrict__ qb, bf16* __restrict__ kb) {
  int s = blockIdx.x, t = threadIdx.x;
  const bf16* Qr = QKV + (size_t)s * 4608;
  const bf16* Kr = Qr + 1536;
  int j0 = t * 6;
  float qv[6], kv[6];
  float sq = 0.f, sk = 0.f;
#pragma unroll
  for (int j = 0; j < 6; ++j) {
    float a = (float)Qr[j0 + j]; qv[j] = a; sq += a * a;
    float b = (float)Kr[j0 + j]; kv[j] = b; sk += b * b;
  }
#pragma unroll
  for (int off = 32; off > 0; off >>= 1) {
    sq += __shfl_down(sq, off);
    sk += __shfl_down(sk, off);
  }
  __shared__ float red[2][4];
  if ((t & 63) == 0) { red[0][t >> 6] = sq; red[1][t >> 6] = sk; }
  __syncthreads();
  float vq = (red[0][0] + red[0][1]) + (red[0][2] + red[0][3]);
  float vk = (red[1][0] + red[1][1]) + (red[1][2] + red[1][3]);
  float rq = 1.0f / sqrtf(vq * (1.0f / 1536.0f) + 1e-6f);
  float rk = 1.0f / sqrtf(vk * (1.0f / 1536.0f) + 1e-6f);
  rq *= 0.08838834764831845f;   // fold attention scale into Q
#pragma unroll
  for (int j = 0; j < 6; j += 2) {
    int jj = j0 + j;
    int d = jj & 127, i = d >> 1, h = jj >> 7;
    float c = tabc[s * 64 + i], sn = tabs[s * 64 + i];
    size_t qbase = (((size_t)h * 3584 + s) << 7) + d;
    float a = qv[j] * rq * gq[jj], b = qv[j + 1] * rq * gq[jj + 1];
    qb[qbase] = (bf16)(a * c - b * sn);
    qb[qbase + 1] = (bf16)(a * sn + b * c);
    // K image: tile = s>>6, r = s&63, swizzled d
    size_t kbase = (((size_t)(h * 56 + (s >> 6)) * 64 + (s & 63)) << 7) + (d ^ ((s & 7) << 3));
    float ak = kv[j] * rk * gk[jj], bk2 = kv[j + 1] * rk * gk[jj + 1];
    kb[kbase] = (bf16)(ak * c - bk2 * sn);
    kb[kbase + 1] = (bf16)(ak * sn + bk2 * c);
  }
}

// ---------------- V -> vT "LDS image": [h][tile=56][drow=128][slot^((drow&7)<<3)] ----------------
__global__ __launch_bounds__(256) void transpose_v(const bf16* __restrict__ QKV,
                                                   bf16* __restrict__ vT) {
  __shared__ bf16 tile[128][72];
  int t = threadIdx.x;
  int h = blockIdx.y;
  int s0 = blockIdx.x * 64;
  int r = t >> 2, c0 = (t & 3) * 32;
  const bf16* src = QKV + (size_t)(s0 + r) * 4608 + 3072 + h * 128 + c0;
#pragma unroll
  for (int q = 0; q < 4; ++q) {
    bf16x8 v = ld8(src + q * 8);
#pragma unroll
    for (int j = 0; j < 8; ++j) tile[c0 + q * 8 + j][r] = v[j];
  }
  __syncthreads();
  int d = t >> 1, spHalf = t & 1;
  int sw = (d & 7) << 3;
  bf16* dstBase = vT + ((size_t)(h * 56 + blockIdx.x) * 128 + d) * 64;
#pragma unroll
  for (int q = 0; q < 4; ++q) {
    int mm = spHalf * 4 + q;
    int sA = 32 * (mm >> 2) + 16 * (mm & 1) + 4 * ((mm >> 1) & 1);
    bf16x4 lo, hi;
#pragma unroll
    for (int j = 0; j < 4; ++j) {
      lo[j] = tile[d][spHalf * 32 + q * 8 + j];
      hi[j] = tile[d][spHalf * 32 + q * 8 + 4 + j];
    }
    int slo = sA ^ sw;
    *(bf16x4*)(dstBase + slo) = lo;
    *(bf16x4*)(dstBase + (slo ^ 8)) = hi;
  }
}

// ---------------- flash attention: R14 base + T5 setprio (ISOLATED A/B) ----------------
// R14 = 130.2 us verified optimum. This round's ONLY change: s_setprio(1/0)
// around the two MFMA clusters (m191: +4-7% for independent-block attn; our
// regime: ~1.4 resident blocks/CU drifting freely). If flash stays 130 +-1.5,
// T5 is null here and flash is declared locally optimal.
// launch_bounds min-waves MUST stay 2 (R4: (256,3) spilled the accumulators).
__global__ __launch_bounds__(256, 2) void flash_attn(
    const bf16* __restrict__ qb, const bf16* __restrict__ kb, const bf16* __restrict__ vT,
    const int* __restrict__ sl, bf16* __restrict__ po0, bf16* __restrict__ po1,
    bf16* __restrict__ po2, bf16* __restrict__ po3, float* __restrict__ ml) {
  const int L = 3584;
  __shared__ bf16 Ks[64 * 128];   // [kv][d], content XOR-swizzled byte ^= ((kv&7)<<4)
  __shared__ bf16 Vs[128 * 64];   // [d][slot], content XOR-swizzled byte ^= ((d&7)<<4)
  int t = threadIdx.x, l = t & 63, w = t >> 6;
  int lane15 = l & 15, lhi = l >> 4;
  int grp48 = l & 48;
  // XCD-locality decode
  int b = blockIdx.x;
  int xcd = b & 7, k_ = b >> 3;
  int pg = k_ / 28, x = k_ - pg * 28;
  int p = pg * 8 + xcd;
  int h = p % 12, z = p / 12;
  int qw = x * 128 + w * 32;
  int seqlen = sl[0];
  bf16* po = (z == 0) ? po0 : (z == 1) ? po1 : (z == 2) ? po2 : po3;
  float* mlz = ml + (size_t)z * 12 * L * 2;

  bf16x8 aq[2][4];
#pragma unroll
  for (int qf = 0; qf < 2; ++qf)
#pragma unroll
    for (int kc = 0; kc < 4; ++kc)
      aq[qf][kc] = ld8(qb + (((size_t)h * L + qw + qf * 16 + lane15) << 7) + kc * 32 + lhi * 8);

  f32x4 zero = {0.f, 0.f, 0.f, 0.f};
  f32x4 out[2][8];
  float m2[2] = {-1e30f, -1e30f}, ls2[2] = {0.f, 0.f};
#pragma unroll
  for (int qf = 0; qf < 2; ++qf)
#pragma unroll
    for (int df = 0; df < 8; ++df) out[qf][df] = zero;

  int nt = (seqlen + 63) >> 6;
  if (nt > 56) nt = 56;
  int t0 = z * 14, t1 = t0 + 14;
  if (t0 > nt) t0 = nt;
  if (t1 > nt) t1 = nt;

  // staging: per-wave uniform LDS dest + lane*16; per-lane linear source
  int src_off = w * 1024 + l * 16;     // bytes within each 4096B quarter
  char* ksd = (char*)Ks + w * 1024;
  char* vsd = (char*)Vs + w * 1024;

  for (int ti = t0; ti < t1; ++ti) {
    int kv0 = ti * 64;
    __syncthreads();   // WAR: all waves done reading previous tile
    {
      const char* kimg = (const char*)kb + ((size_t)(h * 56) + ti) * 16384;
      const char* vimg = (const char*)vT + ((size_t)(h * 56) + ti) * 16384;
#pragma unroll
      for (int pp = 0; pp < 4; ++pp) {
        gload_lds16(kimg + pp * 4096 + src_off, ksd + pp * 4096);
        gload_lds16(vimg + pp * 4096 + src_off, vsd + pp * 4096);
      }
    }
    __syncthreads();   // RAW: drains vmcnt(0); loads are L2-local (XCD map)

    // ---- S^T = mfma(K, Q): lane owns q = lane15; kv = 16a + 4*lhi + r ----
    f32x4 sc[2][4];
#pragma unroll
    for (int qf = 0; qf < 2; ++qf)
#pragma unroll
      for (int a = 0; a < 4; ++a) sc[qf][a] = zero;
    __builtin_amdgcn_s_setprio(1);
#pragma unroll
    for (int a = 0; a < 4; ++a) {
      int rk = a * 16 + lane15;
      const char* krow = (const char*)Ks + rk * 256;
      int swz = (rk & 7) << 4;
#pragma unroll
      for (int kc = 0; kc < 4; ++kc) {
        bf16x8 bk_ = ld8((const bf16*)(krow + ((kc * 64 + lhi * 16) ^ swz)));
        sc[0][a] = __builtin_amdgcn_mfma_f32_16x16x32_bf16(bk_, aq[0][kc], sc[0][a], 0, 0, 0);
        sc[1][a] = __builtin_amdgcn_mfma_f32_16x16x32_bf16(bk_, aq[1][kc], sc[1][a], 0, 0, 0);
      }
    }
    __builtin_amdgcn_s_setprio(0);

    // ---- in-register online softmax (scores already scaled via Q) ----
    bool full = (kv0 + 64 <= seqlen);
    bf16x8 ap[2][2];
#pragma unroll
    for (int qf = 0; qf < 2; ++qf) {
      float tm = -1e30f;
#pragma unroll
      for (int a = 0; a < 4; ++a)
#pragma unroll
        for (int r = 0; r < 4; ++r) {
          float s = sc[qf][a][r];
          if (!full) {
            int col = kv0 + a * 16 + lhi * 4 + r;
            s = (col < seqlen) ? s : -1e30f;
            sc[qf][a][r] = s;
          }
          tm = fmaxf(tm, s);
        }
      tm = fmaxf(tm, __shfl_xor(tm, 16));
      tm = fmaxf(tm, __shfl_xor(tm, 32));
      if (!__all(tm <= m2[qf] + 8.0f)) {   // defer-max: rescale only on real growth
        float nm = fmaxf(m2[qf], tm);
        float f = __expf(m2[qf] - nm);
        m2[qf] = nm;
        ls2[qf] *= f;
#pragma unroll
        for (int r = 0; r < 4; ++r) {
          float fr = __shfl(f, grp48 | (lhi * 4 + r));   // stats live at lane&15 == q
#pragma unroll
          for (int df = 0; df < 8; ++df) out[qf][df][r] *= fr;
        }
      }
      float psum = 0.f;
#pragma unroll
      for (int a = 0; a < 4; ++a)
#pragma unroll
        for (int r = 0; r < 4; ++r) {
          float pv = __expf(sc[qf][a][r] - m2[qf]);
          sc[qf][a][r] = pv;
          psum += pv;
        }
      psum += __shfl_xor(psum, 16);
      psum += __shfl_xor(psum, 32);
      ls2[qf] += psum;
      // PV A-fragments: own values in slot order [p[2c][0..3], p[2c+1][0..3]]
#pragma unroll
      for (int c = 0; c < 2; ++c) {
        bf16x8 f8;
#pragma unroll
        for (int r = 0; r < 4; ++r) {
          f8[r] = (bf16)sc[qf][2 * c][r];
          f8[r + 4] = (bf16)sc[qf][2 * c + 1][r];
        }
        ap[qf][c] = f8;
      }
    }

    // ---- O += P V (V read at matching slots) ----
    __builtin_amdgcn_s_setprio(1);
#pragma unroll
    for (int df = 0; df < 8; ++df) {
      int rd = df * 16 + lane15;
      const char* vrow2 = (const char*)Vs + rd * 128;
      int swz = (rd & 7) << 4;
#pragma unroll
      for (int c = 0; c < 2; ++c) {
        bf16x8 bv_ = ld8((const bf16*)(vrow2 + ((c * 64 + lhi * 16) ^ swz)));
        out[0][df] = __builtin_amdgcn_mfma_f32_16x16x32_bf16(ap[0][c], bv_, out[0][df], 0, 0, 0);
        out[1][df] = __builtin_amdgcn_mfma_f32_16x16x32_bf16(ap[1][c], bv_, out[1][df], 0, 0, 0);
      }
    }
    __builtin_amdgcn_s_setprio(0);
  }

  // ---- write unnormalized partials (bf16) + (m, l) ----
#pragma unroll
  for (int qf = 0; qf < 2; ++qf) {
#pragma unroll
    for (int r = 0; r < 4; ++r) {
      int row = qw + qf * 16 + lhi * 4 + r;
      size_t rbase = ((size_t)h * L + row) << 7;
#pragma unroll
      for (int df = 0; df < 8; ++df)
        po[rbase + df * 16 + lane15] = (bf16)out[qf][df][r];
    }
    if (lhi == 0) {
      int row = qw + qf * 16 + lane15;
      mlz[(((size_t)h * L + row) << 1)] = m2[qf];
      mlz[(((size_t)h * L + row) << 1) + 1] = ls2[qf];
    }
  }
}

// ---------------- combine the four KV-split slices (bf16 partials) ----------------
__global__ __launch_bounds__(256) void combine4(
    const bf16* __restrict__ po0, const bf16* __restrict__ po1,
    const bf16* __restrict__ po2, const bf16* __restrict__ po3,
    const float* __restrict__ ml, bf16* __restrict__ attn) {
  const int L = 3584;
  int row = blockIdx.x * 8 + (threadIdx.x >> 5);   // h*L + s
  int c0 = (threadIdx.x & 31) * 4;
  const size_t mls = (size_t)12 * L * 2;
  float m0 = ml[row * 2],           l0 = ml[row * 2 + 1];
  float m1 = ml[mls + row * 2],     l1 = ml[mls + row * 2 + 1];
  float m2 = ml[2 * mls + row * 2], l2 = ml[2 * mls + row * 2 + 1];
  float m3 = ml[3 * mls + row * 2], l3 = ml[3 * mls + row * 2 + 1];
  float M = fmaxf(fmaxf(m0, m1), fmaxf(m2, m3));
  float w0 = __expf(m0 - M), w1 = __expf(m1 - M);
  float w2 = __expf(m2 - M), w3 = __expf(m3 - M);
  float inv = 1.0f / fmaxf(w0 * l0 + w1 * l1 + w2 * l2 + w3 * l3, 1e-30f);
  bf16x4 a, b, c, d;
  __builtin_memcpy(&a, po0 + (size_t)row * 128 + c0, 8);
  __builtin_memcpy(&b, po1 + (size_t)row * 128 + c0, 8);
  __builtin_memcpy(&c, po2 + (size_t)row * 128 + c0, 8);
  __builtin_memcpy(&d, po3 + (size_t)row * 128 + c0, 8);
  int h = row / L, s = row % L;
  bf16x4 o;
#pragma unroll
  for (int j = 0; j < 4; ++j)
    o[j] = (bf16)((w0 * (float)a[j] + w1 * (float)b[j] + w2 * (float)c[j] + w3 * (float)d[j]) * inv);
  *(bf16x4*)(attn + (size_t)s * 1536 + h * 128 + c0) = o;
}

// ---------------- launcher ----------------
extern "C" void kernel_launch(void* const* d_in, const int* in_sizes, int n_in,
                              void* d_out, int out_size, void* d_ws, size_t ws_size,
                              hipStream_t stream) {
  const float* x = (const float*)d_in[0];
  const int* seq_lens = (const int*)d_in[1];
  const int* grid_sizes = (const int*)d_in[2];
  const float* freqs = (const float*)d_in[3];
  const float* Wq = (const float*)d_in[4];
  const float* bq = (const float*)d_in[5];
  const float* Wk = (const float*)d_in[6];
  const float* bk = (const float*)d_in[7];
  const float* Wv = (const float*)d_in[8];
  const float* bv = (const float*)d_in[9];
  const float* Wo = (const float*)d_in[10];
  const float* bo = (const float*)d_in[11];
  const float* gq = (const float*)d_in[12];
  const float* gk = (const float*)d_in[13];

  char* ws = (char*)d_ws;
  bf16* x_bf = (bf16*)(ws + 0);             // 11,010,048  (dead after QKV GEMM)
  bf16* wqkvt = (bf16*)(ws + 11010048);     // 14,155,776  (dead after QKV GEMM)
  bf16* wot = (bf16*)(ws + 25165824);       //  4,718,592  (live until final GEMM)
  float* bqkv = (float*)(ws + 29884416);    //     18,432
  bf16* QKV = (bf16*)(ws + 29902848);       // 33,030,144  (dead after transpose_v)
  bf16* qb = (bf16*)(ws + 62932992);        // 11,010,048
  bf16* kb = (bf16*)(ws + 73943040);        // 11,010,048  (K image)
  bf16* vT = (bf16*)(ws + 84953088);        // 11,010,048  (V image)
  float* tabc = (float*)(ws + 95963136);    //    917,504  (dead after postproc)
  float* tabs = (float*)(ws + 96880640);    //    917,504  (dead after postproc)
  // overlays for the flash phase (underlying buffers dead by then); bf16 partials
  bf16* po0 = (bf16*)(ws + 29902848);       // 11,010,048 over QKV head
  bf16* attn = (bf16*)(ws + 51922944);      // 11,010,048 over QKV tail
  bf16* po1 = (bf16*)(ws + 0);              // 11,010,048 over x_bf
  bf16* po2 = (bf16*)(ws + 11010048);       // 11,010,048 over wqkvt
  float* ml  = (float*)(ws + 95963136);     //  1,376,256 over tabc+tabs
  bf16* po3 = (bf16*)(ws + 97798144);       // 11,010,048 tail (ends 108,808,192)

  cast_f32_bf16<<<2688, 256, 0, stream>>>(x, x_bf, 688128);
  transpose_w<<<dim3(24, 24), 256, 0, stream>>>(Wq, wqkvt);
  transpose_w<<<dim3(24, 24), 256, 0, stream>>>(Wk, wqkvt + 1536 * 1536);
  transpose_w<<<dim3(24, 24), 256, 0, stream>>>(Wv, wqkvt + 2 * 1536 * 1536);
  transpose_w<<<dim3(24, 24), 256, 0, stream>>>(Wo, wot);
  concat_bias<<<18, 256, 0, stream>>>(bq, bk, bv, bqkv);
  rope_tab<<<896, 256, 0, stream>>>(freqs, grid_sizes, tabc, tabs);
  gemm_bt<bf16><<<1008, 256, 0, stream>>>(x_bf, wqkvt, bqkv, QKV, 3584, 4608, 1536, 28);
  postproc<<<3584, 256, 0, stream>>>(QKV, gq, gk, tabc, tabs, qb, kb);
  transpose_v<<<dim3(56, 12), 256, 0, stream>>>(QKV, vT);
  flash_attn<<<1344, 256, 0, stream>>>(qb, kb, vT, seq_lens, po0, po1, po2, po3, ml);
  combine4<<<5376, 256, 0, stream>>>(po0, po1, po2, po3, ml, attn);
  gemm_bt<float><<<336, 256, 0, stream>>>(attn, wot, bo, (float*)d_out, 3584, 1536, 1536, 28);
}

// Round 16
// 274.292 us; speedup vs baseline: 1.0331x; 1.0331x over previous
//
#include <hip/hip_runtime.h>

typedef __bf16 bf16;
typedef __bf16 bf16x8 __attribute__((ext_vector_type(8)));
typedef __bf16 bf16x4 __attribute__((ext_vector_type(4)));
typedef float f32x4 __attribute__((ext_vector_type(4)));

__device__ __forceinline__ void gload_lds16(const void* g, void* l) {
  __builtin_amdgcn_global_load_lds(
      (const __attribute__((address_space(1))) void*)g,
      (__attribute__((address_space(3))) void*)l, 16, 0, 0);
}

__device__ __forceinline__ bf16x8 ld8(const bf16* p) {
  bf16x8 v; __builtin_memcpy(&v, p, 16); return v;
}

// ---------------- cast x (fp32 -> bf16), 8 elems/thread ----------------
__global__ __launch_bounds__(256) void cast_f32_bf16(const float* __restrict__ in,
                                                     bf16* __restrict__ out, int n8) {
  int i = blockIdx.x * 256 + threadIdx.x;
  if (i >= n8) return;
  const float4* p = (const float4*)in + (size_t)i * 2;
  float4 a = p[0], b = p[1];
  bf16x8 o;
  o[0] = (bf16)a.x; o[1] = (bf16)a.y; o[2] = (bf16)a.z; o[3] = (bf16)a.w;
  o[4] = (bf16)b.x; o[5] = (bf16)b.y; o[6] = (bf16)b.z; o[7] = (bf16)b.w;
  *((bf16x8*)out + i) = o;
}

// ---------------- transpose W (fp32 [K][N]) -> Wt (bf16 [N][K]) ----------------
__global__ __launch_bounds__(256) void transpose_w(const float* __restrict__ W,
                                                   bf16* __restrict__ Wt) {
  __shared__ bf16 tile[64][72];
  int t = threadIdx.x;
  int k0 = blockIdx.x * 64, n0 = blockIdx.y * 64;
  int r = t >> 2, c0 = (t & 3) * 16;
  const float* src = W + (size_t)(k0 + r) * 1536 + n0 + c0;
#pragma unroll
  for (int q = 0; q < 4; ++q) {
    float4 v = *(const float4*)(src + q * 4);
    tile[c0 + q * 4 + 0][r] = (bf16)v.x;
    tile[c0 + q * 4 + 1][r] = (bf16)v.y;
    tile[c0 + q * 4 + 2][r] = (bf16)v.z;
    tile[c0 + q * 4 + 3][r] = (bf16)v.w;
  }
  __syncthreads();
  bf16* dst = Wt + (size_t)(n0 + r) * 1536 + k0 + c0;
  bf16x8 o0, o1;
#pragma unroll
  for (int j = 0; j < 8; ++j) { o0[j] = tile[r][c0 + j]; o1[j] = tile[r][c0 + 8 + j]; }
  *(bf16x8*)dst = o0;
  *(bf16x8*)(dst + 8) = o1;
}

__global__ void concat_bias(const float* __restrict__ bq, const float* __restrict__ bk,
                            const float* __restrict__ bv, float* __restrict__ o) {
  int t = blockIdx.x * 256 + threadIdx.x;
  if (t < 1536) o[t] = bq[t];
  else if (t < 3072) o[t] = bk[t - 1536];
  else if (t < 4608) o[t] = bv[t - 3072];
}

// ---------------- m97-structure GEMM with XCD-locality remap ----------------
template <typename OUT>
__global__ __launch_bounds__(256, 2) void gemm_bt(const bf16* __restrict__ A, const bf16* __restrict__ B,
                                                  const float* __restrict__ bias, OUT* __restrict__ C,
                                                  int M, int N, int K, int gx) {
  __shared__ bf16 As[128 * 32], Bs[128 * 32];
  int t = threadIdx.x, l = t & 63, w = t >> 6;
  int lane15 = l & 15, lhi = l >> 4;
  int b = blockIdx.x;
  int xcd = b & 7, idx = b >> 3;
  int g = xcd * ((int)gridDim.x >> 3) + idx;
  int m0 = (g % gx) * 128, n0 = (g / gx) * 128;
  int wm = (w >> 1) * 64, wn = (w & 1) * 64;
  f32x4 zero = {0.f, 0.f, 0.f, 0.f};
  f32x4 acc[4][4];
#pragma unroll
  for (int i = 0; i < 4; ++i)
#pragma unroll
    for (int j = 0; j < 4; ++j) acc[i][j] = zero;

  int srow = t >> 2, scol = (t & 3) * 8;
  const bf16* gA0 = A + (size_t)(m0 + srow) * K + scol;
  const bf16* gA1 = A + (size_t)(m0 + 64 + srow) * K + scol;
  const bf16* gB0 = B + (size_t)(n0 + srow) * K + scol;
  const bf16* gB1 = B + (size_t)(n0 + 64 + srow) * K + scol;
  char* ldsA = (char*)As + (size_t)w * 1024;
  char* ldsB = (char*)Bs + (size_t)w * 1024;

  for (int kt = 0; kt < K; kt += 32) {
    gload_lds16(gA0 + kt, ldsA);
    gload_lds16(gA1 + kt, ldsA + 4096);
    gload_lds16(gB0 + kt, ldsB);
    gload_lds16(gB1 + kt, ldsB + 4096);
    __syncthreads();
    bf16x8 af[4], bfr[4];
#pragma unroll
    for (int i = 0; i < 4; ++i) {
      af[i]  = ld8(&As[(wm + i * 16 + lane15) * 32 + lhi * 8]);
      bfr[i] = ld8(&Bs[(wn + i * 16 + lane15) * 32 + lhi * 8]);
    }
#pragma unroll
    for (int i = 0; i < 4; ++i)
#pragma unroll
      for (int j = 0; j < 4; ++j)
        acc[i][j] = __builtin_amdgcn_mfma_f32_16x16x32_bf16(af[i], bfr[j], acc[i][j], 0, 0, 0);
    __syncthreads();
  }
#pragma unroll
  for (int i = 0; i < 4; ++i)
#pragma unroll
    for (int j = 0; j < 4; ++j) {
      int col = n0 + wn + j * 16 + lane15;
      float bb = bias[col];
#pragma unroll
      for (int r = 0; r < 4; ++r) {
        int row = m0 + wm + i * 16 + lhi * 4 + r;
        C[(size_t)row * N + col] = (OUT)(acc[i][j][r] + bb);
      }
    }
}

// ---------------- RoPE cos/sin table [3584][64] ----------------
__global__ void rope_tab(const float* __restrict__ freqs, const int* __restrict__ gs,
                         float* __restrict__ tabc, float* __restrict__ tabs) {
  int idx = blockIdx.x * 256 + threadIdx.x;
  if (idx >= 3584 * 64) return;
  int s = idx >> 6, i = idx & 63;
  int H = gs[1], W = gs[2];
  int f = s / (H * W);
  int rem = s - f * (H * W);
  int hh = rem / W;
  int ww = rem - hh * W;
  int row = (i < 22) ? f : ((i < 43) ? hh : ww);
  float a = freqs[row * 64 + i];
  tabc[idx] = cosf(a);
  tabs[idx] = sinf(a);
}

// ---------------- RMSNorm + RoPE for Q,K — VECTORIZED (G13) ----------------
// 192 threads/block, 8 contiguous elements each: bf16x8 loads, float4 trig/gain
// loads, bf16x8 stores (K-image swizzle d^((s&7)<<3) preserves 8-contiguity
// since it only touches bits 3-5 of d). Replaces 24 scalar memops/thread.
// Q pre-scaled by 1/sqrt(128); K written as swizzled "LDS image" (rule #21).
__global__ __launch_bounds__(192) void postproc(const bf16* __restrict__ QKV,
    const float* __restrict__ gq, const float* __restrict__ gk,
    const float* __restrict__ tabc, const float* __restrict__ tabs,
    bf16* __restrict__ qb, bf16* __restrict__ kb) {
  int s = blockIdx.x, t = threadIdx.x;   // t in [0,192)
  const bf16* Qr = QKV + (size_t)s * 4608;
  const bf16* Kr = Qr + 1536;
  int j0 = t * 8;
  bf16x8 qv8 = ld8(Qr + j0);
  bf16x8 kv8 = ld8(Kr + j0);
  float qv[8], kv[8];
  float sq = 0.f, sk = 0.f;
#pragma unroll
  for (int j = 0; j < 8; ++j) {
    qv[j] = (float)qv8[j]; sq += qv[j] * qv[j];
    kv[j] = (float)kv8[j]; sk += kv[j] * kv[j];
  }
#pragma unroll
  for (int off = 32; off > 0; off >>= 1) {
    sq += __shfl_down(sq, off);
    sk += __shfl_down(sk, off);
  }
  __shared__ float red[2][3];
  if ((t & 63) == 0) { red[0][t >> 6] = sq; red[1][t >> 6] = sk; }
  __syncthreads();
  float vq = red[0][0] + red[0][1] + red[0][2];
  float vk = red[1][0] + red[1][1] + red[1][2];
  float rq = 1.0f / sqrtf(vq * (1.0f / 1536.0f) + 1e-6f);
  float rk = 1.0f / sqrtf(vk * (1.0f / 1536.0f) + 1e-6f);
  rq *= 0.08838834764831845f;   // fold attention scale into Q
  int i0 = (j0 >> 1) & 63;      // 4 consecutive table entries, no wrap
  float4 cq = *(const float4*)(tabc + s * 64 + i0);
  float4 sq4 = *(const float4*)(tabs + s * 64 + i0);
  float cc[4] = {cq.x, cq.y, cq.z, cq.w};
  float sn[4] = {sq4.x, sq4.y, sq4.z, sq4.w};
  float4 g0 = *(const float4*)(gq + j0), g1 = *(const float4*)(gq + j0 + 4);
  float4 k0 = *(const float4*)(gk + j0), k1 = *(const float4*)(gk + j0 + 4);
  float gqa[8] = {g0.x, g0.y, g0.z, g0.w, g1.x, g1.y, g1.z, g1.w};
  float gka[8] = {k0.x, k0.y, k0.z, k0.w, k1.x, k1.y, k1.z, k1.w};
  int d0 = j0 & 127, h = j0 >> 7;
  bf16x8 qo, ko;
#pragma unroll
  for (int p = 0; p < 4; ++p) {
    float a = qv[2 * p] * rq * gqa[2 * p];
    float b = qv[2 * p + 1] * rq * gqa[2 * p + 1];
    qo[2 * p] = (bf16)(a * cc[p] - b * sn[p]);
    qo[2 * p + 1] = (bf16)(a * sn[p] + b * cc[p]);
    float ak = kv[2 * p] * rk * gka[2 * p];
    float bk2 = kv[2 * p + 1] * rk * gka[2 * p + 1];
    ko[2 * p] = (bf16)(ak * cc[p] - bk2 * sn[p]);
    ko[2 * p + 1] = (bf16)(ak * sn[p] + bk2 * cc[p]);
  }
  *(bf16x8*)(qb + (((size_t)h * 3584 + s) << 7) + d0) = qo;
  int sw = (s & 7) << 3;
  *(bf16x8*)(kb + (((size_t)(h * 56 + (s >> 6)) * 64 + (s & 63)) << 7) + (d0 ^ sw)) = ko;
}

// ---------------- V -> vT "LDS image": [h][tile=56][drow=128][slot^((drow&7)<<3)] ----------------
__global__ __launch_bounds__(256) void transpose_v(const bf16* __restrict__ QKV,
                                                   bf16* __restrict__ vT) {
  __shared__ bf16 tile[128][72];
  int t = threadIdx.x;
  int h = blockIdx.y;
  int s0 = blockIdx.x * 64;
  int r = t >> 2, c0 = (t & 3) * 32;
  const bf16* src = QKV + (size_t)(s0 + r) * 4608 + 3072 + h * 128 + c0;
#pragma unroll
  for (int q = 0; q < 4; ++q) {
    bf16x8 v = ld8(src + q * 8);
#pragma unroll
    for (int j = 0; j < 8; ++j) tile[c0 + q * 8 + j][r] = v[j];
  }
  __syncthreads();
  int d = t >> 1, spHalf = t & 1;
  int sw = (d & 7) << 3;
  bf16* dstBase = vT + ((size_t)(h * 56 + blockIdx.x) * 128 + d) * 64;
#pragma unroll
  for (int q = 0; q < 4; ++q) {
    int mm = spHalf * 4 + q;
    int sA = 32 * (mm >> 2) + 16 * (mm & 1) + 4 * ((mm >> 1) & 1);
    bf16x4 lo, hi;
#pragma unroll
    for (int j = 0; j < 4; ++j) {
      lo[j] = tile[d][spHalf * 32 + q * 8 + j];
      hi[j] = tile[d][spHalf * 32 + q * 8 + 4 + j];
    }
    int slo = sA ^ sw;
    *(bf16x4*)(dstBase + slo) = lo;
    *(bf16x4*)(dstBase + (slo ^ 8)) = hi;
  }
}

// ---------------- flash attention: R14-EXACT (130.2 us; setprio removed — R15: -5%) ----------------
// Locally optimal config: single 32KB buffer, 2 barriers/tile, zero-register
// gload_lds staging from pre-swizzled images, XCD decode, e-domain softmax
// (exp2f is the slow libm path — R13), defer-max THR=8, no setprio (R15:
// priority inversion between barrier-synced blocks sharing a CU).
// launch_bounds min-waves MUST stay 2 (R4: (256,3) spilled the accumulators).
__global__ __launch_bounds__(256, 2) void flash_attn(
    const bf16* __restrict__ qb, const bf16* __restrict__ kb, const bf16* __restrict__ vT,
    const int* __restrict__ sl, bf16* __restrict__ po0, bf16* __restrict__ po1,
    bf16* __restrict__ po2, bf16* __restrict__ po3, float* __restrict__ ml) {
  const int L = 3584;
  __shared__ bf16 Ks[64 * 128];   // [kv][d], content XOR-swizzled byte ^= ((kv&7)<<4)
  __shared__ bf16 Vs[128 * 64];   // [d][slot], content XOR-swizzled byte ^= ((d&7)<<4)
  int t = threadIdx.x, l = t & 63, w = t >> 6;
  int lane15 = l & 15, lhi = l >> 4;
  int grp48 = l & 48;
  // XCD-locality decode
  int b = blockIdx.x;
  int xcd = b & 7, k_ = b >> 3;
  int pg = k_ / 28, x = k_ - pg * 28;
  int p = pg * 8 + xcd;
  int h = p % 12, z = p / 12;
  int qw = x * 128 + w * 32;
  int seqlen = sl[0];
  bf16* po = (z == 0) ? po0 : (z == 1) ? po1 : (z == 2) ? po2 : po3;
  float* mlz = ml + (size_t)z * 12 * L * 2;

  bf16x8 aq[2][4];
#pragma unroll
  for (int qf = 0; qf < 2; ++qf)
#pragma unroll
    for (int kc = 0; kc < 4; ++kc)
      aq[qf][kc] = ld8(qb + (((size_t)h * L + qw + qf * 16 + lane15) << 7) + kc * 32 + lhi * 8);

  f32x4 zero = {0.f, 0.f, 0.f, 0.f};
  f32x4 out[2][8];
  float m2[2] = {-1e30f, -1e30f}, ls2[2] = {0.f, 0.f};
#pragma unroll
  for (int qf = 0; qf < 2; ++qf)
#pragma unroll
    for (int df = 0; df < 8; ++df) out[qf][df] = zero;

  int nt = (seqlen + 63) >> 6;
  if (nt > 56) nt = 56;
  int t0 = z * 14, t1 = t0 + 14;
  if (t0 > nt) t0 = nt;
  if (t1 > nt) t1 = nt;

  // staging: per-wave uniform LDS dest + lane*16; per-lane linear source
  int src_off = w * 1024 + l * 16;     // bytes within each 4096B quarter
  char* ksd = (char*)Ks + w * 1024;
  char* vsd = (char*)Vs + w * 1024;

  for (int ti = t0; ti < t1; ++ti) {
    int kv0 = ti * 64;
    __syncthreads();   // WAR: all waves done reading previous tile
    {
      const char* kimg = (const char*)kb + ((size_t)(h * 56) + ti) * 16384;
      const char* vimg = (const char*)vT + ((size_t)(h * 56) + ti) * 16384;
#pragma unroll
      for (int pp = 0; pp < 4; ++pp) {
        gload_lds16(kimg + pp * 4096 + src_off, ksd + pp * 4096);
        gload_lds16(vimg + pp * 4096 + src_off, vsd + pp * 4096);
      }
    }
    __syncthreads();   // RAW: drains vmcnt(0); loads are L2-local (XCD map)

    // ---- S^T = mfma(K, Q): lane owns q = lane15; kv = 16a + 4*lhi + r ----
    f32x4 sc[2][4];
#pragma unroll
    for (int qf = 0; qf < 2; ++qf)
#pragma unroll
      for (int a = 0; a < 4; ++a) sc[qf][a] = zero;
#pragma unroll
    for (int a = 0; a < 4; ++a) {
      int rk = a * 16 + lane15;
      const char* krow = (const char*)Ks + rk * 256;
      int swz = (rk & 7) << 4;
#pragma unroll
      for (int kc = 0; kc < 4; ++kc) {
        bf16x8 bk_ = ld8((const bf16*)(krow + ((kc * 64 + lhi * 16) ^ swz)));
        sc[0][a] = __builtin_amdgcn_mfma_f32_16x16x32_bf16(bk_, aq[0][kc], sc[0][a], 0, 0, 0);
        sc[1][a] = __builtin_amdgcn_mfma_f32_16x16x32_bf16(bk_, aq[1][kc], sc[1][a], 0, 0, 0);
      }
    }

    // ---- in-register online softmax (scores already scaled via Q) ----
    bool full = (kv0 + 64 <= seqlen);
    bf16x8 ap[2][2];
#pragma unroll
    for (int qf = 0; qf < 2; ++qf) {
      float tm = -1e30f;
#pragma unroll
      for (int a = 0; a < 4; ++a)
#pragma unroll
        for (int r = 0; r < 4; ++r) {
          float s = sc[qf][a][r];
          if (!full) {
            int col = kv0 + a * 16 + lhi * 4 + r;
            s = (col < seqlen) ? s : -1e30f;
            sc[qf][a][r] = s;
          }
          tm = fmaxf(tm, s);
        }
      tm = fmaxf(tm, __shfl_xor(tm, 16));
      tm = fmaxf(tm, __shfl_xor(tm, 32));
      if (!__all(tm <= m2[qf] + 8.0f)) {   // defer-max: rescale only on real growth
        float nm = fmaxf(m2[qf], tm);
        float f = __expf(m2[qf] - nm);
        m2[qf] = nm;
        ls2[qf] *= f;
#pragma unroll
        for (int r = 0; r < 4; ++r) {
          float fr = __shfl(f, grp48 | (lhi * 4 + r));   // stats live at lane&15 == q
#pragma unroll
          for (int df = 0; df < 8; ++df) out[qf][df][r] *= fr;
        }
      }
      float psum = 0.f;
#pragma unroll
      for (int a = 0; a < 4; ++a)
#pragma unroll
        for (int r = 0; r < 4; ++r) {
          float pv = __expf(sc[qf][a][r] - m2[qf]);
          sc[qf][a][r] = pv;
          psum += pv;
        }
      psum += __shfl_xor(psum, 16);
      psum += __shfl_xor(psum, 32);
      ls2[qf] += psum;
      // PV A-fragments: own values in slot order [p[2c][0..3], p[2c+1][0..3]]
#pragma unroll
      for (int c = 0; c < 2; ++c) {
        bf16x8 f8;
#pragma unroll
        for (int r = 0; r < 4; ++r) {
          f8[r] = (bf16)sc[qf][2 * c][r];
          f8[r + 4] = (bf16)sc[qf][2 * c + 1][r];
        }
        ap[qf][c] = f8;
      }
    }

    // ---- O += P V (V read at matching slots) ----
#pragma unroll
    for (int df = 0; df < 8; ++df) {
      int rd = df * 16 + lane15;
      const char* vrow2 = (const char*)Vs + rd * 128;
      int swz = (rd & 7) << 4;
#pragma unroll
      for (int c = 0; c < 2; ++c) {
        bf16x8 bv_ = ld8((const bf16*)(vrow2 + ((c * 64 + lhi * 16) ^ swz)));
        out[0][df] = __builtin_amdgcn_mfma_f32_16x16x32_bf16(ap[0][c], bv_, out[0][df], 0, 0, 0);
        out[1][df] = __builtin_amdgcn_mfma_f32_16x16x32_bf16(ap[1][c], bv_, out[1][df], 0, 0, 0);
      }
    }
  }

  // ---- write unnormalized partials (bf16) + (m, l) ----
#pragma unroll
  for (int qf = 0; qf < 2; ++qf) {
#pragma unroll
    for (int r = 0; r < 4; ++r) {
      int row = qw + qf * 16 + lhi * 4 + r;
      size_t rbase = ((size_t)h * L + row) << 7;
#pragma unroll
      for (int df = 0; df < 8; ++df)
        po[rbase + df * 16 + lane15] = (bf16)out[qf][df][r];
    }
    if (lhi == 0) {
      int row = qw + qf * 16 + lane15;
      mlz[(((size_t)h * L + row) << 1)] = m2[qf];
      mlz[(((size_t)h * L + row) << 1) + 1] = ls2[qf];
    }
  }
}

// ---------------- combine the four KV-split slices (bf16 partials) ----------------
__global__ __launch_bounds__(256) void combine4(
    const bf16* __restrict__ po0, const bf16* __restrict__ po1,
    const bf16* __restrict__ po2, const bf16* __restrict__ po3,
    const float* __restrict__ ml, bf16* __restrict__ attn) {
  const int L = 3584;
  int row = blockIdx.x * 8 + (threadIdx.x >> 5);   // h*L + s
  int c0 = (threadIdx.x & 31) * 4;
  const size_t mls = (size_t)12 * L * 2;
  float m0 = ml[row * 2],           l0 = ml[row * 2 + 1];
  float m1 = ml[mls + row * 2],     l1 = ml[mls + row * 2 + 1];
  float m2 = ml[2 * mls + row * 2], l2 = ml[2 * mls + row * 2 + 1];
  float m3 = ml[3 * mls + row * 2], l3 = ml[3 * mls + row * 2 + 1];
  float M = fmaxf(fmaxf(m0, m1), fmaxf(m2, m3));
  float w0 = __expf(m0 - M), w1 = __expf(m1 - M);
  float w2 = __expf(m2 - M), w3 = __expf(m3 - M);
  float inv = 1.0f / fmaxf(w0 * l0 + w1 * l1 + w2 * l2 + w3 * l3, 1e-30f);
  bf16x4 a, b, c, d;
  __builtin_memcpy(&a, po0 + (size_t)row * 128 + c0, 8);
  __builtin_memcpy(&b, po1 + (size_t)row * 128 + c0, 8);
  __builtin_memcpy(&c, po2 + (size_t)row * 128 + c0, 8);
  __builtin_memcpy(&d, po3 + (size_t)row * 128 + c0, 8);
  int h = row / L, s = row % L;
  bf16x4 o;
#pragma unroll
  for (int j = 0; j < 4; ++j)
    o[j] = (bf16)((w0 * (float)a[j] + w1 * (float)b[j] + w2 * (float)c[j] + w3 * (float)d[j]) * inv);
  *(bf16x4*)(attn + (size_t)s * 1536 + h * 128 + c0) = o;
}

// ---------------- launcher ----------------
extern "C" void kernel_launch(void* const* d_in, const int* in_sizes, int n_in,
                              void* d_out, int out_size, void* d_ws, size_t ws_size,
                              hipStream_t stream) {
  const float* x = (const float*)d_in[0];
  const int* seq_lens = (const int*)d_in[1];
  const int* grid_sizes = (const int*)d_in[2];
  const float* freqs = (const float*)d_in[3];
  const float* Wq = (const float*)d_in[4];
  const float* bq = (const float*)d_in[5];
  const float* Wk = (const float*)d_in[6];
  const float* bk = (const float*)d_in[7];
  const float* Wv = (const float*)d_in[8];
  const float* bv = (const float*)d_in[9];
  const float* Wo = (const float*)d_in[10];
  const float* bo = (const float*)d_in[11];
  const float* gq = (const float*)d_in[12];
  const float* gk = (const float*)d_in[13];

  char* ws = (char*)d_ws;
  bf16* x_bf = (bf16*)(ws + 0);             // 11,010,048  (dead after QKV GEMM)
  bf16* wqkvt = (bf16*)(ws + 11010048);     // 14,155,776  (dead after QKV GEMM)
  bf16* wot = (bf16*)(ws + 25165824);       //  4,718,592  (live until final GEMM)
  float* bqkv = (float*)(ws + 29884416);    //     18,432
  bf16* QKV = (bf16*)(ws + 29902848);       // 33,030,144  (dead after transpose_v)
  bf16* qb = (bf16*)(ws + 62932992);        // 11,010,048
  bf16* kb = (bf16*)(ws + 73943040);        // 11,010,048  (K image)
  bf16* vT = (bf16*)(ws + 84953088);        // 11,010,048  (V image)
  float* tabc = (float*)(ws + 95963136);    //    917,504  (dead after postproc)
  float* tabs = (float*)(ws + 96880640);    //    917,504  (dead after postproc)
  // overlays for the flash phase (underlying buffers dead by then); bf16 partials
  bf16* po0 = (bf16*)(ws + 29902848);       // 11,010,048 over QKV head
  bf16* attn = (bf16*)(ws + 51922944);      // 11,010,048 over QKV tail
  bf16* po1 = (bf16*)(ws + 0);              // 11,010,048 over x_bf
  bf16* po2 = (bf16*)(ws + 11010048);       // 11,010,048 over wqkvt
  float* ml  = (float*)(ws + 95963136);     //  1,376,256 over tabc+tabs
  bf16* po3 = (bf16*)(ws + 97798144);       // 11,010,048 tail (ends 108,808,192)

  cast_f32_bf16<<<2688, 256, 0, stream>>>(x, x_bf, 688128);
  transpose_w<<<dim3(24, 24), 256, 0, stream>>>(Wq, wqkvt);
  transpose_w<<<dim3(24, 24), 256, 0, stream>>>(Wk, wqkvt + 1536 * 1536);
  transpose_w<<<dim3(24, 24), 256, 0, stream>>>(Wv, wqkvt + 2 * 1536 * 1536);
  transpose_w<<<dim3(24, 24), 256, 0, stream>>>(Wo, wot);
  concat_bias<<<18, 256, 0, stream>>>(bq, bk, bv, bqkv);
  rope_tab<<<896, 256, 0, stream>>>(freqs, grid_sizes, tabc, tabs);
  gemm_bt<bf16><<<1008, 256, 0, stream>>>(x_bf, wqkvt, bqkv, QKV, 3584, 4608, 1536, 28);
  postproc<<<3584, 192, 0, stream>>>(QKV, gq, gk, tabc, tabs, qb, kb);
  transpose_v<<<dim3(56, 12), 256, 0, stream>>>(QKV, vT);
  flash_attn<<<1344, 256, 0, stream>>>(qb, kb, vT, seq_lens, po0, po1, po2, po3, ml);
  combine4<<<5376, 256, 0, stream>>>(po0, po1, po2, po3, ml, attn);
  gemm_bt<float><<<336, 256, 0, stream>>>(attn, wot, bo, (float*)d_out, 3584, 1536, 1536, 28);
}

// Round 17
// 268.288 us; speedup vs baseline: 1.0562x; 1.0224x over previous
//
#include <hip/hip_runtime.h>

typedef __bf16 bf16;
typedef __bf16 bf16x8 __attribute__((ext_vector_type(8)));
typedef __bf16 bf16x4 __attribute__((ext_vector_type(4)));
typedef float f32x4 __attribute__((ext_vector_type(4)));

__device__ __forceinline__ void gload_lds16(const void* g, void* l) {
  __builtin_amdgcn_global_load_lds(
      (const __attribute__((address_space(1))) void*)g,
      (__attribute__((address_space(3))) void*)l, 16, 0, 0);
}

__device__ __forceinline__ bf16x8 ld8(const bf16* p) {
  bf16x8 v; __builtin_memcpy(&v, p, 16); return v;
}

// ---------------- cast x (fp32 -> bf16), 8 elems/thread ----------------
__global__ __launch_bounds__(256) void cast_f32_bf16(const float* __restrict__ in,
                                                     bf16* __restrict__ out, int n8) {
  int i = blockIdx.x * 256 + threadIdx.x;
  if (i >= n8) return;
  const float4* p = (const float4*)in + (size_t)i * 2;
  float4 a = p[0], b = p[1];
  bf16x8 o;
  o[0] = (bf16)a.x; o[1] = (bf16)a.y; o[2] = (bf16)a.z; o[3] = (bf16)a.w;
  o[4] = (bf16)b.x; o[5] = (bf16)b.y; o[6] = (bf16)b.z; o[7] = (bf16)b.w;
  *((bf16x8*)out + i) = o;
}

// ---------------- transpose 3x W (fp32 [K][N]) -> Wt (bf16 [N][K]), z-indexed ----------------
__global__ __launch_bounds__(256) void transpose_w3(const float* __restrict__ Wq,
                                                    const float* __restrict__ Wk,
                                                    const float* __restrict__ Wv,
                                                    bf16* __restrict__ Wt) {
  __shared__ bf16 tile[64][72];
  int t = threadIdx.x;
  int z = blockIdx.z;
  const float* W = (z == 0) ? Wq : (z == 1) ? Wk : Wv;
  bf16* dstM = Wt + (size_t)z * 1536 * 1536;
  int k0 = blockIdx.x * 64, n0 = blockIdx.y * 64;
  int r = t >> 2, c0 = (t & 3) * 16;
  const float* src = W + (size_t)(k0 + r) * 1536 + n0 + c0;
#pragma unroll
  for (int q = 0; q < 4; ++q) {
    float4 v = *(const float4*)(src + q * 4);
    tile[c0 + q * 4 + 0][r] = (bf16)v.x;
    tile[c0 + q * 4 + 1][r] = (bf16)v.y;
    tile[c0 + q * 4 + 2][r] = (bf16)v.z;
    tile[c0 + q * 4 + 3][r] = (bf16)v.w;
  }
  __syncthreads();
  bf16* dst = dstM + (size_t)(n0 + r) * 1536 + k0 + c0;
  bf16x8 o0, o1;
#pragma unroll
  for (int j = 0; j < 8; ++j) { o0[j] = tile[r][c0 + j]; o1[j] = tile[r][c0 + 8 + j]; }
  *(bf16x8*)dst = o0;
  *(bf16x8*)(dst + 8) = o1;
}

// ---------------- single transpose W (for Wo) ----------------
__global__ __launch_bounds__(256) void transpose_w(const float* __restrict__ W,
                                                   bf16* __restrict__ Wt) {
  __shared__ bf16 tile[64][72];
  int t = threadIdx.x;
  int k0 = blockIdx.x * 64, n0 = blockIdx.y * 64;
  int r = t >> 2, c0 = (t & 3) * 16;
  const float* src = W + (size_t)(k0 + r) * 1536 + n0 + c0;
#pragma unroll
  for (int q = 0; q < 4; ++q) {
    float4 v = *(const float4*)(src + q * 4);
    tile[c0 + q * 4 + 0][r] = (bf16)v.x;
    tile[c0 + q * 4 + 1][r] = (bf16)v.y;
    tile[c0 + q * 4 + 2][r] = (bf16)v.z;
    tile[c0 + q * 4 + 3][r] = (bf16)v.w;
  }
  __syncthreads();
  bf16* dst = Wt + (size_t)(n0 + r) * 1536 + k0 + c0;
  bf16x8 o0, o1;
#pragma unroll
  for (int j = 0; j < 8; ++j) { o0[j] = tile[r][c0 + j]; o1[j] = tile[r][c0 + 8 + j]; }
  *(bf16x8*)dst = o0;
  *(bf16x8*)(dst + 8) = o1;
}

// ---------------- m97-structure GEMM with XCD-locality remap ----------------
template <typename OUT>
__global__ __launch_bounds__(256, 2) void gemm_bt(const bf16* __restrict__ A, const bf16* __restrict__ B,
                                                  const float* __restrict__ bias, OUT* __restrict__ C,
                                                  int M, int N, int K, int gx) {
  __shared__ bf16 As[128 * 32], Bs[128 * 32];
  int t = threadIdx.x, l = t & 63, w = t >> 6;
  int lane15 = l & 15, lhi = l >> 4;
  int b = blockIdx.x;
  int xcd = b & 7, idx = b >> 3;
  int g = xcd * ((int)gridDim.x >> 3) + idx;
  int m0 = (g % gx) * 128, n0 = (g / gx) * 128;
  int wm = (w >> 1) * 64, wn = (w & 1) * 64;
  f32x4 zero = {0.f, 0.f, 0.f, 0.f};
  f32x4 acc[4][4];
#pragma unroll
  for (int i = 0; i < 4; ++i)
#pragma unroll
    for (int j = 0; j < 4; ++j) acc[i][j] = zero;

  int srow = t >> 2, scol = (t & 3) * 8;
  const bf16* gA0 = A + (size_t)(m0 + srow) * K + scol;
  const bf16* gA1 = A + (size_t)(m0 + 64 + srow) * K + scol;
  const bf16* gB0 = B + (size_t)(n0 + srow) * K + scol;
  const bf16* gB1 = B + (size_t)(n0 + 64 + srow) * K + scol;
  char* ldsA = (char*)As + (size_t)w * 1024;
  char* ldsB = (char*)Bs + (size_t)w * 1024;

  for (int kt = 0; kt < K; kt += 32) {
    gload_lds16(gA0 + kt, ldsA);
    gload_lds16(gA1 + kt, ldsA + 4096);
    gload_lds16(gB0 + kt, ldsB);
    gload_lds16(gB1 + kt, ldsB + 4096);
    __syncthreads();
    bf16x8 af[4], bfr[4];
#pragma unroll
    for (int i = 0; i < 4; ++i) {
      af[i]  = ld8(&As[(wm + i * 16 + lane15) * 32 + lhi * 8]);
      bfr[i] = ld8(&Bs[(wn + i * 16 + lane15) * 32 + lhi * 8]);
    }
#pragma unroll
    for (int i = 0; i < 4; ++i)
#pragma unroll
      for (int j = 0; j < 4; ++j)
        acc[i][j] = __builtin_amdgcn_mfma_f32_16x16x32_bf16(af[i], bfr[j], acc[i][j], 0, 0, 0);
    __syncthreads();
  }
#pragma unroll
  for (int i = 0; i < 4; ++i)
#pragma unroll
    for (int j = 0; j < 4; ++j) {
      int col = n0 + wn + j * 16 + lane15;
      float bb = bias[col];
#pragma unroll
      for (int r = 0; r < 4; ++r) {
        int row = m0 + wm + i * 16 + lhi * 4 + r;
        C[(size_t)row * N + col] = (OUT)(acc[i][j][r] + bb);
      }
    }
}

// ---------------- RoPE cos/sin table [3584][64] + bias concat (fused) ----------------
__global__ void rope_bias(const float* __restrict__ freqs, const int* __restrict__ gs,
                          float* __restrict__ tabc, float* __restrict__ tabs,
                          const float* __restrict__ bq, const float* __restrict__ bk,
                          const float* __restrict__ bv, float* __restrict__ bqkv) {
  int idx = blockIdx.x * 256 + threadIdx.x;
  if (idx < 4608) {   // bias concat (blocks 0..17 contribute)
    bqkv[idx] = (idx < 1536) ? bq[idx] : (idx < 3072) ? bk[idx - 1536] : bv[idx - 3072];
  }
  if (idx >= 3584 * 64) return;
  int s = idx >> 6, i = idx & 63;
  int H = gs[1], W = gs[2];
  int f = s / (H * W);
  int rem = s - f * (H * W);
  int hh = rem / W;
  int ww = rem - hh * W;
  int row = (i < 22) ? f : ((i < 43) ? hh : ww);
  float a = freqs[row * 64 + i];
  tabc[idx] = cosf(a);
  tabs[idx] = sinf(a);
}

// ---------------- RMSNorm + RoPE for Q,K — VECTORIZED (G13) ----------------
__global__ __launch_bounds__(192) void postproc(const bf16* __restrict__ QKV,
    const float* __restrict__ gq, const float* __restrict__ gk,
    const float* __restrict__ tabc, const float* __restrict__ tabs,
    bf16* __restrict__ qb, bf16* __restrict__ kb) {
  int s = blockIdx.x, t = threadIdx.x;   // t in [0,192)
  const bf16* Qr = QKV + (size_t)s * 4608;
  const bf16* Kr = Qr + 1536;
  int j0 = t * 8;
  bf16x8 qv8 = ld8(Qr + j0);
  bf16x8 kv8 = ld8(Kr + j0);
  float qv[8], kv[8];
  float sq = 0.f, sk = 0.f;
#pragma unroll
  for (int j = 0; j < 8; ++j) {
    qv[j] = (float)qv8[j]; sq += qv[j] * qv[j];
    kv[j] = (float)kv8[j]; sk += kv[j] * kv[j];
  }
#pragma unroll
  for (int off = 32; off > 0; off >>= 1) {
    sq += __shfl_down(sq, off);
    sk += __shfl_down(sk, off);
  }
  __shared__ float red[2][3];
  if ((t & 63) == 0) { red[0][t >> 6] = sq; red[1][t >> 6] = sk; }
  __syncthreads();
  float vq = red[0][0] + red[0][1] + red[0][2];
  float vk = red[1][0] + red[1][1] + red[1][2];
  float rq = 1.0f / sqrtf(vq * (1.0f / 1536.0f) + 1e-6f);
  float rk = 1.0f / sqrtf(vk * (1.0f / 1536.0f) + 1e-6f);
  rq *= 0.08838834764831845f;   // fold attention scale into Q
  int i0 = (j0 >> 1) & 63;
  float4 cq = *(const float4*)(tabc + s * 64 + i0);
  float4 sq4 = *(const float4*)(tabs + s * 64 + i0);
  float cc[4] = {cq.x, cq.y, cq.z, cq.w};
  float sn[4] = {sq4.x, sq4.y, sq4.z, sq4.w};
  float4 g0 = *(const float4*)(gq + j0), g1 = *(const float4*)(gq + j0 + 4);
  float4 k0 = *(const float4*)(gk + j0), k1 = *(const float4*)(gk + j0 + 4);
  float gqa[8] = {g0.x, g0.y, g0.z, g0.w, g1.x, g1.y, g1.z, g1.w};
  float gka[8] = {k0.x, k0.y, k0.z, k0.w, k1.x, k1.y, k1.z, k1.w};
  int d0 = j0 & 127, h = j0 >> 7;
  bf16x8 qo, ko;
#pragma unroll
  for (int p = 0; p < 4; ++p) {
    float a = qv[2 * p] * rq * gqa[2 * p];
    float b = qv[2 * p + 1] * rq * gqa[2 * p + 1];
    qo[2 * p] = (bf16)(a * cc[p] - b * sn[p]);
    qo[2 * p + 1] = (bf16)(a * sn[p] + b * cc[p]);
    float ak = kv[2 * p] * rk * gka[2 * p];
    float bk2 = kv[2 * p + 1] * rk * gka[2 * p + 1];
    ko[2 * p] = (bf16)(ak * cc[p] - bk2 * sn[p]);
    ko[2 * p + 1] = (bf16)(ak * sn[p] + bk2 * cc[p]);
  }
  *(bf16x8*)(qb + (((size_t)h * 3584 + s) << 7) + d0) = qo;
  int sw = (s & 7) << 3;
  *(bf16x8*)(kb + (((size_t)(h * 56 + (s >> 6)) * 64 + (s & 63)) << 7) + (d0 ^ sw)) = ko;
}

// ---------------- V -> vT "LDS image": [h][tile=56][drow=128][slot^((drow&7)<<3)] ----------------
__global__ __launch_bounds__(256) void transpose_v(const bf16* __restrict__ QKV,
                                                   bf16* __restrict__ vT) {
  __shared__ bf16 tile[128][72];
  int t = threadIdx.x;
  int h = blockIdx.y;
  int s0 = blockIdx.x * 64;
  int r = t >> 2, c0 = (t & 3) * 32;
  const bf16* src = QKV + (size_t)(s0 + r) * 4608 + 3072 + h * 128 + c0;
#pragma unroll
  for (int q = 0; q < 4; ++q) {
    bf16x8 v = ld8(src + q * 8);
#pragma unroll
    for (int j = 0; j < 8; ++j) tile[c0 + q * 8 + j][r] = v[j];
  }
  __syncthreads();
  int d = t >> 1, spHalf = t & 1;
  int sw = (d & 7) << 3;
  bf16* dstBase = vT + ((size_t)(h * 56 + blockIdx.x) * 128 + d) * 64;
#pragma unroll
  for (int q = 0; q < 4; ++q) {
    int mm = spHalf * 4 + q;
    int sA = 32 * (mm >> 2) + 16 * (mm & 1) + 4 * ((mm >> 1) & 1);
    bf16x4 lo, hi;
#pragma unroll
    for (int j = 0; j < 4; ++j) {
      lo[j] = tile[d][spHalf * 32 + q * 8 + j];
      hi[j] = tile[d][spHalf * 32 + q * 8 + 4 + j];
    }
    int slo = sA ^ sw;
    *(bf16x4*)(dstBase + slo) = lo;
    *(bf16x4*)(dstBase + (slo ^ 8)) = hi;
  }
}

// ---------------- flash attention: R14-EXACT (130.2 us verified optimum) ----------------
// Single 32KB buffer, 2 barriers/tile, zero-register gload_lds staging from
// pre-swizzled images, XCD decode, e-domain softmax (exp2f = slow libm, R13),
// defer-max THR=8, no setprio (R15: priority inversion, -5%).
// launch_bounds min-waves MUST stay 2 (R4: (256,3) spilled the accumulators).
__global__ __launch_bounds__(256, 2) void flash_attn(
    const bf16* __restrict__ qb, const bf16* __restrict__ kb, const bf16* __restrict__ vT,
    const int* __restrict__ sl, bf16* __restrict__ po0, bf16* __restrict__ po1,
    bf16* __restrict__ po2, bf16* __restrict__ po3, float* __restrict__ ml) {
  const int L = 3584;
  __shared__ bf16 Ks[64 * 128];   // [kv][d], content XOR-swizzled byte ^= ((kv&7)<<4)
  __shared__ bf16 Vs[128 * 64];   // [d][slot], content XOR-swizzled byte ^= ((d&7)<<4)
  int t = threadIdx.x, l = t & 63, w = t >> 6;
  int lane15 = l & 15, lhi = l >> 4;
  int grp48 = l & 48;
  // XCD-locality decode
  int b = blockIdx.x;
  int xcd = b & 7, k_ = b >> 3;
  int pg = k_ / 28, x = k_ - pg * 28;
  int p = pg * 8 + xcd;
  int h = p % 12, z = p / 12;
  int qw = x * 128 + w * 32;
  int seqlen = sl[0];
  bf16* po = (z == 0) ? po0 : (z == 1) ? po1 : (z == 2) ? po2 : po3;
  float* mlz = ml + (size_t)z * 12 * L * 2;

  bf16x8 aq[2][4];
#pragma unroll
  for (int qf = 0; qf < 2; ++qf)
#pragma unroll
    for (int kc = 0; kc < 4; ++kc)
      aq[qf][kc] = ld8(qb + (((size_t)h * L + qw + qf * 16 + lane15) << 7) + kc * 32 + lhi * 8);

  f32x4 zero = {0.f, 0.f, 0.f, 0.f};
  f32x4 out[2][8];
  float m2[2] = {-1e30f, -1e30f}, ls2[2] = {0.f, 0.f};
#pragma unroll
  for (int qf = 0; qf < 2; ++qf)
#pragma unroll
    for (int df = 0; df < 8; ++df) out[qf][df] = zero;

  int nt = (seqlen + 63) >> 6;
  if (nt > 56) nt = 56;
  int t0 = z * 14, t1 = t0 + 14;
  if (t0 > nt) t0 = nt;
  if (t1 > nt) t1 = nt;

  int src_off = w * 1024 + l * 16;
  char* ksd = (char*)Ks + w * 1024;
  char* vsd = (char*)Vs + w * 1024;

  for (int ti = t0; ti < t1; ++ti) {
    int kv0 = ti * 64;
    __syncthreads();   // WAR: all waves done reading previous tile
    {
      const char* kimg = (const char*)kb + ((size_t)(h * 56) + ti) * 16384;
      const char* vimg = (const char*)vT + ((size_t)(h * 56) + ti) * 16384;
#pragma unroll
      for (int pp = 0; pp < 4; ++pp) {
        gload_lds16(kimg + pp * 4096 + src_off, ksd + pp * 4096);
        gload_lds16(vimg + pp * 4096 + src_off, vsd + pp * 4096);
      }
    }
    __syncthreads();   // RAW: drains vmcnt(0); loads are L2-local (XCD map)

    // ---- S^T = mfma(K, Q): lane owns q = lane15; kv = 16a + 4*lhi + r ----
    f32x4 sc[2][4];
#pragma unroll
    for (int qf = 0; qf < 2; ++qf)
#pragma unroll
      for (int a = 0; a < 4; ++a) sc[qf][a] = zero;
#pragma unroll
    for (int a = 0; a < 4; ++a) {
      int rk = a * 16 + lane15;
      const char* krow = (const char*)Ks + rk * 256;
      int swz = (rk & 7) << 4;
#pragma unroll
      for (int kc = 0; kc < 4; ++kc) {
        bf16x8 bk_ = ld8((const bf16*)(krow + ((kc * 64 + lhi * 16) ^ swz)));
        sc[0][a] = __builtin_amdgcn_mfma_f32_16x16x32_bf16(bk_, aq[0][kc], sc[0][a], 0, 0, 0);
        sc[1][a] = __builtin_amdgcn_mfma_f32_16x16x32_bf16(bk_, aq[1][kc], sc[1][a], 0, 0, 0);
      }
    }

    // ---- in-register online softmax (scores already scaled via Q) ----
    bool full = (kv0 + 64 <= seqlen);
    bf16x8 ap[2][2];
#pragma unroll
    for (int qf = 0; qf < 2; ++qf) {
      float tm = -1e30f;
#pragma unroll
      for (int a = 0; a < 4; ++a)
#pragma unroll
        for (int r = 0; r < 4; ++r) {
          float s = sc[qf][a][r];
          if (!full) {
            int col = kv0 + a * 16 + lhi * 4 + r;
            s = (col < seqlen) ? s : -1e30f;
            sc[qf][a][r] = s;
          }
          tm = fmaxf(tm, s);
        }
      tm = fmaxf(tm, __shfl_xor(tm, 16));
      tm = fmaxf(tm, __shfl_xor(tm, 32));
      if (!__all(tm <= m2[qf] + 8.0f)) {   // defer-max: rescale only on real growth
        float nm = fmaxf(m2[qf], tm);
        float f = __expf(m2[qf] - nm);
        m2[qf] = nm;
        ls2[qf] *= f;
#pragma unroll
        for (int r = 0; r < 4; ++r) {
          float fr = __shfl(f, grp48 | (lhi * 4 + r));   // stats live at lane&15 == q
#pragma unroll
          for (int df = 0; df < 8; ++df) out[qf][df][r] *= fr;
        }
      }
      float psum = 0.f;
#pragma unroll
      for (int a = 0; a < 4; ++a)
#pragma unroll
        for (int r = 0; r < 4; ++r) {
          float pv = __expf(sc[qf][a][r] - m2[qf]);
          sc[qf][a][r] = pv;
          psum += pv;
        }
      psum += __shfl_xor(psum, 16);
      psum += __shfl_xor(psum, 32);
      ls2[qf] += psum;
#pragma unroll
      for (int c = 0; c < 2; ++c) {
        bf16x8 f8;
#pragma unroll
        for (int r = 0; r < 4; ++r) {
          f8[r] = (bf16)sc[qf][2 * c][r];
          f8[r + 4] = (bf16)sc[qf][2 * c + 1][r];
        }
        ap[qf][c] = f8;
      }
    }

    // ---- O += P V (V read at matching slots) ----
#pragma unroll
    for (int df = 0; df < 8; ++df) {
      int rd = df * 16 + lane15;
      const char* vrow2 = (const char*)Vs + rd * 128;
      int swz = (rd & 7) << 4;
#pragma unroll
      for (int c = 0; c < 2; ++c) {
        bf16x8 bv_ = ld8((const bf16*)(vrow2 + ((c * 64 + lhi * 16) ^ swz)));
        out[0][df] = __builtin_amdgcn_mfma_f32_16x16x32_bf16(ap[0][c], bv_, out[0][df], 0, 0, 0);
        out[1][df] = __builtin_amdgcn_mfma_f32_16x16x32_bf16(ap[1][c], bv_, out[1][df], 0, 0, 0);
      }
    }
  }

  // ---- write unnormalized partials (bf16) + (m, l) ----
#pragma unroll
  for (int qf = 0; qf < 2; ++qf) {
#pragma unroll
    for (int r = 0; r < 4; ++r) {
      int row = qw + qf * 16 + lhi * 4 + r;
      size_t rbase = ((size_t)h * L + row) << 7;
#pragma unroll
      for (int df = 0; df < 8; ++df)
        po[rbase + df * 16 + lane15] = (bf16)out[qf][df][r];
    }
    if (lhi == 0) {
      int row = qw + qf * 16 + lane15;
      mlz[(((size_t)h * L + row) << 1)] = m2[qf];
      mlz[(((size_t)h * L + row) << 1) + 1] = ls2[qf];
    }
  }
}

// ---------------- combine the four KV-split slices (bf16 partials) ----------------
__global__ __launch_bounds__(256) void combine4(
    const bf16* __restrict__ po0, const bf16* __restrict__ po1,
    const bf16* __restrict__ po2, const bf16* __restrict__ po3,
    const float* __restrict__ ml, bf16* __restrict__ attn) {
  const int L = 3584;
  int row = blockIdx.x * 8 + (threadIdx.x >> 5);   // h*L + s
  int c0 = (threadIdx.x & 31) * 4;
  const size_t mls = (size_t)12 * L * 2;
  float m0 = ml[row * 2],           l0 = ml[row * 2 + 1];
  float m1 = ml[mls + row * 2],     l1 = ml[mls + row * 2 + 1];
  float m2 = ml[2 * mls + row * 2], l2 = ml[2 * mls + row * 2 + 1];
  float m3 = ml[3 * mls + row * 2], l3 = ml[3 * mls + row * 2 + 1];
  float M = fmaxf(fmaxf(m0, m1), fmaxf(m2, m3));
  float w0 = __expf(m0 - M), w1 = __expf(m1 - M);
  float w2 = __expf(m2 - M), w3 = __expf(m3 - M);
  float inv = 1.0f / fmaxf(w0 * l0 + w1 * l1 + w2 * l2 + w3 * l3, 1e-30f);
  bf16x4 a, b, c, d;
  __builtin_memcpy(&a, po0 + (size_t)row * 128 + c0, 8);
  __builtin_memcpy(&b, po1 + (size_t)row * 128 + c0, 8);
  __builtin_memcpy(&c, po2 + (size_t)row * 128 + c0, 8);
  __builtin_memcpy(&d, po3 + (size_t)row * 128 + c0, 8);
  int h = row / L, s = row % L;
  bf16x4 o;
#pragma unroll
  for (int j = 0; j < 4; ++j)
    o[j] = (bf16)((w0 * (float)a[j] + w1 * (float)b[j] + w2 * (float)c[j] + w3 * (float)d[j]) * inv);
  *(bf16x4*)(attn + (size_t)s * 1536 + h * 128 + c0) = o;
}

// ---------------- launcher ----------------
extern "C" void kernel_launch(void* const* d_in, const int* in_sizes, int n_in,
                              void* d_out, int out_size, void* d_ws, size_t ws_size,
                              hipStream_t stream) {
  const float* x = (const float*)d_in[0];
  const int* seq_lens = (const int*)d_in[1];
  const int* grid_sizes = (const int*)d_in[2];
  const float* freqs = (const float*)d_in[3];
  const float* Wq = (const float*)d_in[4];
  const float* bq = (const float*)d_in[5];
  const float* Wk = (const float*)d_in[6];
  const float* bk = (const float*)d_in[7];
  const float* Wv = (const float*)d_in[8];
  const float* bv = (const float*)d_in[9];
  const float* Wo = (const float*)d_in[10];
  const float* bo = (const float*)d_in[11];
  const float* gq = (const float*)d_in[12];
  const float* gk = (const float*)d_in[13];

  char* ws = (char*)d_ws;
  bf16* x_bf = (bf16*)(ws + 0);             // 11,010,048  (dead after QKV GEMM)
  bf16* wqkvt = (bf16*)(ws + 11010048);     // 14,155,776  (dead after QKV GEMM)
  bf16* wot = (bf16*)(ws + 25165824);       //  4,718,592  (live until final GEMM)
  float* bqkv = (float*)(ws + 29884416);    //     18,432
  bf16* QKV = (bf16*)(ws + 29902848);       // 33,030,144  (dead after transpose_v)
  bf16* qb = (bf16*)(ws + 62932992);        // 11,010,048
  bf16* kb = (bf16*)(ws + 73943040);        // 11,010,048  (K image)
  bf16* vT = (bf16*)(ws + 84953088);        // 11,010,048  (V image)
  float* tabc = (float*)(ws + 95963136);    //    917,504  (dead after postproc)
  float* tabs = (float*)(ws + 96880640);    //    917,504  (dead after postproc)
  // overlays for the flash phase (underlying buffers dead by then); bf16 partials
  bf16* po0 = (bf16*)(ws + 29902848);       // 11,010,048 over QKV head
  bf16* attn = (bf16*)(ws + 51922944);      // 11,010,048 over QKV tail
  bf16* po1 = (bf16*)(ws + 0);              // 11,010,048 over x_bf
  bf16* po2 = (bf16*)(ws + 11010048);       // 11,010,048 over wqkvt
  float* ml  = (float*)(ws + 95963136);     //  1,376,256 over tabc+tabs
  bf16* po3 = (bf16*)(ws + 97798144);       // 11,010,048 tail (ends 108,808,192)

  cast_f32_bf16<<<2688, 256, 0, stream>>>(x, x_bf, 688128);
  transpose_w3<<<dim3(24, 24, 3), 256, 0, stream>>>(Wq, Wk, Wv, wqkvt);
  transpose_w<<<dim3(24, 24), 256, 0, stream>>>(Wo, wot);
  rope_bias<<<896, 256, 0, stream>>>(freqs, grid_sizes, tabc, tabs, bq, bk, bv, bqkv);
  gemm_bt<bf16><<<1008, 256, 0, stream>>>(x_bf, wqkvt, bqkv, QKV, 3584, 4608, 1536, 28);
  postproc<<<3584, 192, 0, stream>>>(QKV, gq, gk, tabc, tabs, qb, kb);
  transpose_v<<<dim3(56, 12), 256, 0, stream>>>(QKV, vT);
  flash_attn<<<1344, 256, 0, stream>>>(qb, kb, vT, seq_lens, po0, po1, po2, po3, ml);
  combine4<<<5376, 256, 0, stream>>>(po0, po1, po2, po3, ml, attn);
  gemm_bt<float><<<336, 256, 0, stream>>>(attn, wot, bo, (float*)d_out, 3584, 1536, 1536, 28);
}

// Round 18
// 261.203 us; speedup vs baseline: 1.0848x; 1.0271x over previous
//
#include <hip/hip_runtime.h>

typedef __bf16 bf16;
typedef __bf16 bf16x8 __attribute__((ext_vector_type(8)));
typedef __bf16 bf16x4 __attribute__((ext_vector_type(4)));
typedef float f32x4 __attribute__((ext_vector_type(4)));

__device__ __forceinline__ void gload_lds16(const void* g, void* l) {
  __builtin_amdgcn_global_load_lds(
      (const __attribute__((address_space(1))) void*)g,
      (__attribute__((address_space(3))) void*)l, 16, 0, 0);
}

__device__ __forceinline__ bf16x8 ld8(const bf16* p) {
  bf16x8 v; __builtin_memcpy(&v, p, 16); return v;
}

// ---------------- fused prologue: cast | W-transposes | rope-tab+bias ----------------
// Block-range dispatch (branch is block-uniform):
//   [0,2688)      : cast x fp32->bf16 (8 elems/thread)
//   [2688,4416)   : transpose Wq/Wk/Wv -> wqkvt (bf16 [N][K]), z = idx/576
//   [4416,4992)   : transpose Wo -> wot
//   [4992,5888)   : RoPE cos/sin table + bias concat
__global__ __launch_bounds__(256) void prologue(
    const float* __restrict__ x, const float* __restrict__ Wq, const float* __restrict__ Wk,
    const float* __restrict__ Wv, const float* __restrict__ Wo,
    const float* __restrict__ freqs, const int* __restrict__ gs,
    const float* __restrict__ bq, const float* __restrict__ bk, const float* __restrict__ bv,
    bf16* __restrict__ x_bf, bf16* __restrict__ wqkvt, bf16* __restrict__ wot,
    float* __restrict__ tabc, float* __restrict__ tabs, float* __restrict__ bqkv) {
  __shared__ bf16 tile[64][72];
  int b = blockIdx.x, t = threadIdx.x;
  if (b < 2688) {
    int i = b * 256 + t;                      // always < 688128
    const float4* p = (const float4*)x + (size_t)i * 2;
    float4 a = p[0], v2 = p[1];
    bf16x8 o;
    o[0] = (bf16)a.x;  o[1] = (bf16)a.y;  o[2] = (bf16)a.z;  o[3] = (bf16)a.w;
    o[4] = (bf16)v2.x; o[5] = (bf16)v2.y; o[6] = (bf16)v2.z; o[7] = (bf16)v2.w;
    *((bf16x8*)x_bf + i) = o;
  } else if (b < 4992) {
    const float* W; bf16* dstM; int xy;
    if (b < 4416) {
      int idx = b - 2688; int z = idx / 576; xy = idx % 576;
      W = (z == 0) ? Wq : (z == 1) ? Wk : Wv;
      dstM = wqkvt + (size_t)z * 1536 * 1536;
    } else {
      xy = b - 4416; W = Wo; dstM = wot;
    }
    int k0 = (xy % 24) * 64, n0 = (xy / 24) * 64;
    int r = t >> 2, c0 = (t & 3) * 16;
    const float* src = W + (size_t)(k0 + r) * 1536 + n0 + c0;
#pragma unroll
    for (int q = 0; q < 4; ++q) {
      float4 v = *(const float4*)(src + q * 4);
      tile[c0 + q * 4 + 0][r] = (bf16)v.x;
      tile[c0 + q * 4 + 1][r] = (bf16)v.y;
      tile[c0 + q * 4 + 2][r] = (bf16)v.z;
      tile[c0 + q * 4 + 3][r] = (bf16)v.w;
    }
    __syncthreads();
    bf16* dst = dstM + (size_t)(n0 + r) * 1536 + k0 + c0;
    bf16x8 o0, o1;
#pragma unroll
    for (int j = 0; j < 8; ++j) { o0[j] = tile[r][c0 + j]; o1[j] = tile[r][c0 + 8 + j]; }
    *(bf16x8*)dst = o0;
    *(bf16x8*)(dst + 8) = o1;
  } else {
    int idx = (b - 4992) * 256 + t;           // < 229376 = 3584*64
    if (idx < 4608)
      bqkv[idx] = (idx < 1536) ? bq[idx] : (idx < 3072) ? bk[idx - 1536] : bv[idx - 3072];
    int s = idx >> 6, i = idx & 63;
    int H = gs[1], Wd = gs[2];
    int f = s / (H * Wd);
    int rem = s - f * (H * Wd);
    int hh = rem / Wd;
    int ww = rem - hh * Wd;
    int row = (i < 22) ? f : ((i < 43) ? hh : ww);
    float a = freqs[row * 64 + i];
    tabc[idx] = cosf(a);
    tabs[idx] = sinf(a);
  }
}

// ---------------- m97-structure GEMM with XCD-locality remap ----------------
template <typename OUT>
__global__ __launch_bounds__(256, 2) void gemm_bt(const bf16* __restrict__ A, const bf16* __restrict__ B,
                                                  const float* __restrict__ bias, OUT* __restrict__ C,
                                                  int M, int N, int K, int gx) {
  __shared__ bf16 As[128 * 32], Bs[128 * 32];
  int t = threadIdx.x, l = t & 63, w = t >> 6;
  int lane15 = l & 15, lhi = l >> 4;
  int b = blockIdx.x;
  int xcd = b & 7, idx = b >> 3;
  int g = xcd * ((int)gridDim.x >> 3) + idx;
  int m0 = (g % gx) * 128, n0 = (g / gx) * 128;
  int wm = (w >> 1) * 64, wn = (w & 1) * 64;
  f32x4 zero = {0.f, 0.f, 0.f, 0.f};
  f32x4 acc[4][4];
#pragma unroll
  for (int i = 0; i < 4; ++i)
#pragma unroll
    for (int j = 0; j < 4; ++j) acc[i][j] = zero;

  int srow = t >> 2, scol = (t & 3) * 8;
  const bf16* gA0 = A + (size_t)(m0 + srow) * K + scol;
  const bf16* gA1 = A + (size_t)(m0 + 64 + srow) * K + scol;
  const bf16* gB0 = B + (size_t)(n0 + srow) * K + scol;
  const bf16* gB1 = B + (size_t)(n0 + 64 + srow) * K + scol;
  char* ldsA = (char*)As + (size_t)w * 1024;
  char* ldsB = (char*)Bs + (size_t)w * 1024;

  for (int kt = 0; kt < K; kt += 32) {
    gload_lds16(gA0 + kt, ldsA);
    gload_lds16(gA1 + kt, ldsA + 4096);
    gload_lds16(gB0 + kt, ldsB);
    gload_lds16(gB1 + kt, ldsB + 4096);
    __syncthreads();
    bf16x8 af[4], bfr[4];
#pragma unroll
    for (int i = 0; i < 4; ++i) {
      af[i]  = ld8(&As[(wm + i * 16 + lane15) * 32 + lhi * 8]);
      bfr[i] = ld8(&Bs[(wn + i * 16 + lane15) * 32 + lhi * 8]);
    }
#pragma unroll
    for (int i = 0; i < 4; ++i)
#pragma unroll
      for (int j = 0; j < 4; ++j)
        acc[i][j] = __builtin_amdgcn_mfma_f32_16x16x32_bf16(af[i], bfr[j], acc[i][j], 0, 0, 0);
    __syncthreads();
  }
#pragma unroll
  for (int i = 0; i < 4; ++i)
#pragma unroll
    for (int j = 0; j < 4; ++j) {
      int col = n0 + wn + j * 16 + lane15;
      float bb = bias[col];
#pragma unroll
      for (int r = 0; r < 4; ++r) {
        int row = m0 + wm + i * 16 + lhi * 4 + r;
        C[(size_t)row * N + col] = (OUT)(acc[i][j][r] + bb);
      }
    }
}

// ---------------- RMSNorm + RoPE for Q,K — VECTORIZED (G13) ----------------
__global__ __launch_bounds__(192) void postproc(const bf16* __restrict__ QKV,
    const float* __restrict__ gq, const float* __restrict__ gk,
    const float* __restrict__ tabc, const float* __restrict__ tabs,
    bf16* __restrict__ qb, bf16* __restrict__ kb) {
  int s = blockIdx.x, t = threadIdx.x;   // t in [0,192)
  const bf16* Qr = QKV + (size_t)s * 4608;
  const bf16* Kr = Qr + 1536;
  int j0 = t * 8;
  bf16x8 qv8 = ld8(Qr + j0);
  bf16x8 kv8 = ld8(Kr + j0);
  float qv[8], kv[8];
  float sq = 0.f, sk = 0.f;
#pragma unroll
  for (int j = 0; j < 8; ++j) {
    qv[j] = (float)qv8[j]; sq += qv[j] * qv[j];
    kv[j] = (float)kv8[j]; sk += kv[j] * kv[j];
  }
#pragma unroll
  for (int off = 32; off > 0; off >>= 1) {
    sq += __shfl_down(sq, off);
    sk += __shfl_down(sk, off);
  }
  __shared__ float red[2][3];
  if ((t & 63) == 0) { red[0][t >> 6] = sq; red[1][t >> 6] = sk; }
  __syncthreads();
  float vq = red[0][0] + red[0][1] + red[0][2];
  float vk = red[1][0] + red[1][1] + red[1][2];
  float rq = 1.0f / sqrtf(vq * (1.0f / 1536.0f) + 1e-6f);
  float rk = 1.0f / sqrtf(vk * (1.0f / 1536.0f) + 1e-6f);
  rq *= 0.08838834764831845f;   // fold attention scale into Q
  int i0 = (j0 >> 1) & 63;
  float4 cq = *(const float4*)(tabc + s * 64 + i0);
  float4 sq4 = *(const float4*)(tabs + s * 64 + i0);
  float cc[4] = {cq.x, cq.y, cq.z, cq.w};
  float sn[4] = {sq4.x, sq4.y, sq4.z, sq4.w};
  float4 g0 = *(const float4*)(gq + j0), g1 = *(const float4*)(gq + j0 + 4);
  float4 k0 = *(const float4*)(gk + j0), k1 = *(const float4*)(gk + j0 + 4);
  float gqa[8] = {g0.x, g0.y, g0.z, g0.w, g1.x, g1.y, g1.z, g1.w};
  float gka[8] = {k0.x, k0.y, k0.z, k0.w, k1.x, k1.y, k1.z, k1.w};
  int d0 = j0 & 127, h = j0 >> 7;
  bf16x8 qo, ko;
#pragma unroll
  for (int p = 0; p < 4; ++p) {
    float a = qv[2 * p] * rq * gqa[2 * p];
    float b = qv[2 * p + 1] * rq * gqa[2 * p + 1];
    qo[2 * p] = (bf16)(a * cc[p] - b * sn[p]);
    qo[2 * p + 1] = (bf16)(a * sn[p] + b * cc[p]);
    float ak = kv[2 * p] * rk * gka[2 * p];
    float bk2 = kv[2 * p + 1] * rk * gka[2 * p + 1];
    ko[2 * p] = (bf16)(ak * cc[p] - bk2 * sn[p]);
    ko[2 * p + 1] = (bf16)(ak * sn[p] + bk2 * cc[p]);
  }
  *(bf16x8*)(qb + (((size_t)h * 3584 + s) << 7) + d0) = qo;
  int sw = (s & 7) << 3;
  *(bf16x8*)(kb + (((size_t)(h * 56 + (s >> 6)) * 64 + (s & 63)) << 7) + (d0 ^ sw)) = ko;
}

// ---------------- V -> vT "LDS image": [h][tile=56][drow=128][slot^((drow&7)<<3)] ----------------
__global__ __launch_bounds__(256) void transpose_v(const bf16* __restrict__ QKV,
                                                   bf16* __restrict__ vT) {
  __shared__ bf16 tile[128][72];
  int t = threadIdx.x;
  int h = blockIdx.y;
  int s0 = blockIdx.x * 64;
  int r = t >> 2, c0 = (t & 3) * 32;
  const bf16* src = QKV + (size_t)(s0 + r) * 4608 + 3072 + h * 128 + c0;
#pragma unroll
  for (int q = 0; q < 4; ++q) {
    bf16x8 v = ld8(src + q * 8);
#pragma unroll
    for (int j = 0; j < 8; ++j) tile[c0 + q * 8 + j][r] = v[j];
  }
  __syncthreads();
  int d = t >> 1, spHalf = t & 1;
  int sw = (d & 7) << 3;
  bf16* dstBase = vT + ((size_t)(h * 56 + blockIdx.x) * 128 + d) * 64;
#pragma unroll
  for (int q = 0; q < 4; ++q) {
    int mm = spHalf * 4 + q;
    int sA = 32 * (mm >> 2) + 16 * (mm & 1) + 4 * ((mm >> 1) & 1);
    bf16x4 lo, hi;
#pragma unroll
    for (int j = 0; j < 4; ++j) {
      lo[j] = tile[d][spHalf * 32 + q * 8 + j];
      hi[j] = tile[d][spHalf * 32 + q * 8 + 4 + j];
    }
    int slo = sA ^ sw;
    *(bf16x4*)(dstBase + slo) = lo;
    *(bf16x4*)(dstBase + (slo ^ 8)) = hi;
  }
}

// ---------------- flash attention: R14-EXACT (130.2 us verified optimum) ----------------
// Single 32KB buffer, 2 barriers/tile, zero-register gload_lds staging from
// pre-swizzled images, XCD decode, e-domain softmax (exp2f = slow libm, R13),
// defer-max THR=8, no setprio (R15: priority inversion, -5%).
// launch_bounds min-waves MUST stay 2 (R4: (256,3) spilled the accumulators).
__global__ __launch_bounds__(256, 2) void flash_attn(
    const bf16* __restrict__ qb, const bf16* __restrict__ kb, const bf16* __restrict__ vT,
    const int* __restrict__ sl, bf16* __restrict__ po0, bf16* __restrict__ po1,
    bf16* __restrict__ po2, bf16* __restrict__ po3, float* __restrict__ ml) {
  const int L = 3584;
  __shared__ bf16 Ks[64 * 128];   // [kv][d], content XOR-swizzled byte ^= ((kv&7)<<4)
  __shared__ bf16 Vs[128 * 64];   // [d][slot], content XOR-swizzled byte ^= ((d&7)<<4)
  int t = threadIdx.x, l = t & 63, w = t >> 6;
  int lane15 = l & 15, lhi = l >> 4;
  int grp48 = l & 48;
  int b = blockIdx.x;
  int xcd = b & 7, k_ = b >> 3;
  int pg = k_ / 28, x = k_ - pg * 28;
  int p = pg * 8 + xcd;
  int h = p % 12, z = p / 12;
  int qw = x * 128 + w * 32;
  int seqlen = sl[0];
  bf16* po = (z == 0) ? po0 : (z == 1) ? po1 : (z == 2) ? po2 : po3;
  float* mlz = ml + (size_t)z * 12 * L * 2;

  bf16x8 aq[2][4];
#pragma unroll
  for (int qf = 0; qf < 2; ++qf)
#pragma unroll
    for (int kc = 0; kc < 4; ++kc)
      aq[qf][kc] = ld8(qb + (((size_t)h * L + qw + qf * 16 + lane15) << 7) + kc * 32 + lhi * 8);

  f32x4 zero = {0.f, 0.f, 0.f, 0.f};
  f32x4 out[2][8];
  float m2[2] = {-1e30f, -1e30f}, ls2[2] = {0.f, 0.f};
#pragma unroll
  for (int qf = 0; qf < 2; ++qf)
#pragma unroll
    for (int df = 0; df < 8; ++df) out[qf][df] = zero;

  int nt = (seqlen + 63) >> 6;
  if (nt > 56) nt = 56;
  int t0 = z * 14, t1 = t0 + 14;
  if (t0 > nt) t0 = nt;
  if (t1 > nt) t1 = nt;

  int src_off = w * 1024 + l * 16;
  char* ksd = (char*)Ks + w * 1024;
  char* vsd = (char*)Vs + w * 1024;

  for (int ti = t0; ti < t1; ++ti) {
    int kv0 = ti * 64;
    __syncthreads();   // WAR: all waves done reading previous tile
    {
      const char* kimg = (const char*)kb + ((size_t)(h * 56) + ti) * 16384;
      const char* vimg = (const char*)vT + ((size_t)(h * 56) + ti) * 16384;
#pragma unroll
      for (int pp = 0; pp < 4; ++pp) {
        gload_lds16(kimg + pp * 4096 + src_off, ksd + pp * 4096);
        gload_lds16(vimg + pp * 4096 + src_off, vsd + pp * 4096);
      }
    }
    __syncthreads();   // RAW: drains vmcnt(0); loads are L2-local (XCD map)

    // ---- S^T = mfma(K, Q): lane owns q = lane15; kv = 16a + 4*lhi + r ----
    f32x4 sc[2][4];
#pragma unroll
    for (int qf = 0; qf < 2; ++qf)
#pragma unroll
      for (int a = 0; a < 4; ++a) sc[qf][a] = zero;
#pragma unroll
    for (int a = 0; a < 4; ++a) {
      int rk = a * 16 + lane15;
      const char* krow = (const char*)Ks + rk * 256;
      int swz = (rk & 7) << 4;
#pragma unroll
      for (int kc = 0; kc < 4; ++kc) {
        bf16x8 bk_ = ld8((const bf16*)(krow + ((kc * 64 + lhi * 16) ^ swz)));
        sc[0][a] = __builtin_amdgcn_mfma_f32_16x16x32_bf16(bk_, aq[0][kc], sc[0][a], 0, 0, 0);
        sc[1][a] = __builtin_amdgcn_mfma_f32_16x16x32_bf16(bk_, aq[1][kc], sc[1][a], 0, 0, 0);
      }
    }

    // ---- in-register online softmax (scores already scaled via Q) ----
    bool full = (kv0 + 64 <= seqlen);
    bf16x8 ap[2][2];
#pragma unroll
    for (int qf = 0; qf < 2; ++qf) {
      float tm = -1e30f;
#pragma unroll
      for (int a = 0; a < 4; ++a)
#pragma unroll
        for (int r = 0; r < 4; ++r) {
          float s = sc[qf][a][r];
          if (!full) {
            int col = kv0 + a * 16 + lhi * 4 + r;
            s = (col < seqlen) ? s : -1e30f;
            sc[qf][a][r] = s;
          }
          tm = fmaxf(tm, s);
        }
      tm = fmaxf(tm, __shfl_xor(tm, 16));
      tm = fmaxf(tm, __shfl_xor(tm, 32));
      if (!__all(tm <= m2[qf] + 8.0f)) {   // defer-max: rescale only on real growth
        float nm = fmaxf(m2[qf], tm);
        float f = __expf(m2[qf] - nm);
        m2[qf] = nm;
        ls2[qf] *= f;
#pragma unroll
        for (int r = 0; r < 4; ++r) {
          float fr = __shfl(f, grp48 | (lhi * 4 + r));   // stats live at lane&15 == q
#pragma unroll
          for (int df = 0; df < 8; ++df) out[qf][df][r] *= fr;
        }
      }
      float psum = 0.f;
#pragma unroll
      for (int a = 0; a < 4; ++a)
#pragma unroll
        for (int r = 0; r < 4; ++r) {
          float pv = __expf(sc[qf][a][r] - m2[qf]);
          sc[qf][a][r] = pv;
          psum += pv;
        }
      psum += __shfl_xor(psum, 16);
      psum += __shfl_xor(psum, 32);
      ls2[qf] += psum;
#pragma unroll
      for (int c = 0; c < 2; ++c) {
        bf16x8 f8;
#pragma unroll
        for (int r = 0; r < 4; ++r) {
          f8[r] = (bf16)sc[qf][2 * c][r];
          f8[r + 4] = (bf16)sc[qf][2 * c + 1][r];
        }
        ap[qf][c] = f8;
      }
    }

    // ---- O += P V (V read at matching slots) ----
#pragma unroll
    for (int df = 0; df < 8; ++df) {
      int rd = df * 16 + lane15;
      const char* vrow2 = (const char*)Vs + rd * 128;
      int swz = (rd & 7) << 4;
#pragma unroll
      for (int c = 0; c < 2; ++c) {
        bf16x8 bv_ = ld8((const bf16*)(vrow2 + ((c * 64 + lhi * 16) ^ swz)));
        out[0][df] = __builtin_amdgcn_mfma_f32_16x16x32_bf16(ap[0][c], bv_, out[0][df], 0, 0, 0);
        out[1][df] = __builtin_amdgcn_mfma_f32_16x16x32_bf16(ap[1][c], bv_, out[1][df], 0, 0, 0);
      }
    }
  }

  // ---- write unnormalized partials (bf16) + (m, l) ----
#pragma unroll
  for (int qf = 0; qf < 2; ++qf) {
#pragma unroll
    for (int r = 0; r < 4; ++r) {
      int row = qw + qf * 16 + lhi * 4 + r;
      size_t rbase = ((size_t)h * L + row) << 7;
#pragma unroll
      for (int df = 0; df < 8; ++df)
        po[rbase + df * 16 + lane15] = (bf16)out[qf][df][r];
    }
    if (lhi == 0) {
      int row = qw + qf * 16 + lane15;
      mlz[(((size_t)h * L + row) << 1)] = m2[qf];
      mlz[(((size_t)h * L + row) << 1) + 1] = ls2[qf];
    }
  }
}

// ---------------- combine the four KV-split slices — bf16x8 vectorized ----------------
__global__ __launch_bounds__(256) void combine4(
    const bf16* __restrict__ po0, const bf16* __restrict__ po1,
    const bf16* __restrict__ po2, const bf16* __restrict__ po3,
    const float* __restrict__ ml, bf16* __restrict__ attn) {
  const int L = 3584;
  int row = blockIdx.x * 16 + (threadIdx.x >> 4);   // h*L + s; 2688 blocks
  int c0 = (threadIdx.x & 15) * 8;
  const size_t mls = (size_t)12 * L * 2;
  float m0 = ml[row * 2],           l0 = ml[row * 2 + 1];
  float m1 = ml[mls + row * 2],     l1 = ml[mls + row * 2 + 1];
  float m2 = ml[2 * mls + row * 2], l2 = ml[2 * mls + row * 2 + 1];
  float m3 = ml[3 * mls + row * 2], l3 = ml[3 * mls + row * 2 + 1];
  float M = fmaxf(fmaxf(m0, m1), fmaxf(m2, m3));
  float w0 = __expf(m0 - M), w1 = __expf(m1 - M);
  float w2 = __expf(m2 - M), w3 = __expf(m3 - M);
  float inv = 1.0f / fmaxf(w0 * l0 + w1 * l1 + w2 * l2 + w3 * l3, 1e-30f);
  bf16x8 a = ld8(po0 + (size_t)row * 128 + c0);
  bf16x8 b = ld8(po1 + (size_t)row * 128 + c0);
  bf16x8 c = ld8(po2 + (size_t)row * 128 + c0);
  bf16x8 d = ld8(po3 + (size_t)row * 128 + c0);
  int h = row / L, s = row % L;
  bf16x8 o;
#pragma unroll
  for (int j = 0; j < 8; ++j)
    o[j] = (bf16)((w0 * (float)a[j] + w1 * (float)b[j] + w2 * (float)c[j] + w3 * (float)d[j]) * inv);
  *(bf16x8*)(attn + (size_t)s * 1536 + h * 128 + c0) = o;
}

// ---------------- launcher ----------------
extern "C" void kernel_launch(void* const* d_in, const int* in_sizes, int n_in,
                              void* d_out, int out_size, void* d_ws, size_t ws_size,
                              hipStream_t stream) {
  const float* x = (const float*)d_in[0];
  const int* seq_lens = (const int*)d_in[1];
  const int* grid_sizes = (const int*)d_in[2];
  const float* freqs = (const float*)d_in[3];
  const float* Wq = (const float*)d_in[4];
  const float* bq = (const float*)d_in[5];
  const float* Wk = (const float*)d_in[6];
  const float* bk = (const float*)d_in[7];
  const float* Wv = (const float*)d_in[8];
  const float* bv = (const float*)d_in[9];
  const float* Wo = (const float*)d_in[10];
  const float* bo = (const float*)d_in[11];
  const float* gq = (const float*)d_in[12];
  const float* gk = (const float*)d_in[13];

  char* ws = (char*)d_ws;
  bf16* x_bf = (bf16*)(ws + 0);             // 11,010,048  (dead after QKV GEMM)
  bf16* wqkvt = (bf16*)(ws + 11010048);     // 14,155,776  (dead after QKV GEMM)
  bf16* wot = (bf16*)(ws + 25165824);       //  4,718,592  (live until final GEMM)
  float* bqkv = (float*)(ws + 29884416);    //     18,432
  bf16* QKV = (bf16*)(ws + 29902848);       // 33,030,144  (dead after transpose_v)
  bf16* qb = (bf16*)(ws + 62932992);        // 11,010,048
  bf16* kb = (bf16*)(ws + 73943040);        // 11,010,048  (K image)
  bf16* vT = (bf16*)(ws + 84953088);        // 11,010,048  (V image)
  float* tabc = (float*)(ws + 95963136);    //    917,504  (dead after postproc)
  float* tabs = (float*)(ws + 96880640);    //    917,504  (dead after postproc)
  // overlays for the flash phase (underlying buffers dead by then); bf16 partials
  bf16* po0 = (bf16*)(ws + 29902848);       // 11,010,048 over QKV head
  bf16* attn = (bf16*)(ws + 51922944);      // 11,010,048 over QKV tail
  bf16* po1 = (bf16*)(ws + 0);              // 11,010,048 over x_bf
  bf16* po2 = (bf16*)(ws + 11010048);       // 11,010,048 over wqkvt
  float* ml  = (float*)(ws + 95963136);     //  1,376,256 over tabc+tabs
  bf16* po3 = (bf16*)(ws + 97798144);       // 11,010,048 tail (ends 108,808,192)

  prologue<<<5888, 256, 0, stream>>>(x, Wq, Wk, Wv, Wo, freqs, grid_sizes, bq, bk, bv,
                                     x_bf, wqkvt, wot, tabc, tabs, bqkv);
  gemm_bt<bf16><<<1008, 256, 0, stream>>>(x_bf, wqkvt, bqkv, QKV, 3584, 4608, 1536, 28);
  postproc<<<3584, 192, 0, stream>>>(QKV, gq, gk, tabc, tabs, qb, kb);
  transpose_v<<<dim3(56, 12), 256, 0, stream>>>(QKV, vT);
  flash_attn<<<1344, 256, 0, stream>>>(qb, kb, vT, seq_lens, po0, po1, po2, po3, ml);
  combine4<<<2688, 256, 0, stream>>>(po0, po1, po2, po3, ml, attn);
  gemm_bt<float><<<336, 256, 0, stream>>>(attn, wot, bo, (float*)d_out, 3584, 1536, 1536, 28);
}

// Round 19
// 259.687 us; speedup vs baseline: 1.0912x; 1.0058x over previous
//
#include <hip/hip_runtime.h>

typedef __bf16 bf16;
typedef __bf16 bf16x8 __attribute__((ext_vector_type(8)));
typedef __bf16 bf16x4 __attribute__((ext_vector_type(4)));
typedef float f32x4 __attribute__((ext_vector_type(4)));

__device__ __forceinline__ void gload_lds16(const void* g, void* l) {
  __builtin_amdgcn_global_load_lds(
      (const __attribute__((address_space(1))) void*)g,
      (__attribute__((address_space(3))) void*)l, 16, 0, 0);
}

__device__ __forceinline__ bf16x8 ld8(const bf16* p) {
  bf16x8 v; __builtin_memcpy(&v, p, 16); return v;
}

// ---------------- fused prologue: cast | W-transposes | rope-tab+bias ----------------
__global__ __launch_bounds__(256) void prologue(
    const float* __restrict__ x, const float* __restrict__ Wq, const float* __restrict__ Wk,
    const float* __restrict__ Wv, const float* __restrict__ Wo,
    const float* __restrict__ freqs, const int* __restrict__ gs,
    const float* __restrict__ bq, const float* __restrict__ bk, const float* __restrict__ bv,
    bf16* __restrict__ x_bf, bf16* __restrict__ wqkvt, bf16* __restrict__ wot,
    float* __restrict__ tabc, float* __restrict__ tabs, float* __restrict__ bqkv) {
  __shared__ bf16 tile[64][72];
  int b = blockIdx.x, t = threadIdx.x;
  if (b < 2688) {
    int i = b * 256 + t;
    const float4* p = (const float4*)x + (size_t)i * 2;
    float4 a = p[0], v2 = p[1];
    bf16x8 o;
    o[0] = (bf16)a.x;  o[1] = (bf16)a.y;  o[2] = (bf16)a.z;  o[3] = (bf16)a.w;
    o[4] = (bf16)v2.x; o[5] = (bf16)v2.y; o[6] = (bf16)v2.z; o[7] = (bf16)v2.w;
    *((bf16x8*)x_bf + i) = o;
  } else if (b < 4992) {
    const float* W; bf16* dstM; int xy;
    if (b < 4416) {
      int idx = b - 2688; int z = idx / 576; xy = idx % 576;
      W = (z == 0) ? Wq : (z == 1) ? Wk : Wv;
      dstM = wqkvt + (size_t)z * 1536 * 1536;
    } else {
      xy = b - 4416; W = Wo; dstM = wot;
    }
    int k0 = (xy % 24) * 64, n0 = (xy / 24) * 64;
    int r = t >> 2, c0 = (t & 3) * 16;
    const float* src = W + (size_t)(k0 + r) * 1536 + n0 + c0;
#pragma unroll
    for (int q = 0; q < 4; ++q) {
      float4 v = *(const float4*)(src + q * 4);
      tile[c0 + q * 4 + 0][r] = (bf16)v.x;
      tile[c0 + q * 4 + 1][r] = (bf16)v.y;
      tile[c0 + q * 4 + 2][r] = (bf16)v.z;
      tile[c0 + q * 4 + 3][r] = (bf16)v.w;
    }
    __syncthreads();
    bf16* dst = dstM + (size_t)(n0 + r) * 1536 + k0 + c0;
    bf16x8 o0, o1;
#pragma unroll
    for (int j = 0; j < 8; ++j) { o0[j] = tile[r][c0 + j]; o1[j] = tile[r][c0 + 8 + j]; }
    *(bf16x8*)dst = o0;
    *(bf16x8*)(dst + 8) = o1;
  } else {
    int idx = (b - 4992) * 256 + t;
    if (idx < 4608)
      bqkv[idx] = (idx < 1536) ? bq[idx] : (idx < 3072) ? bk[idx - 1536] : bv[idx - 3072];
    int s = idx >> 6, i = idx & 63;
    int H = gs[1], Wd = gs[2];
    int f = s / (H * Wd);
    int rem = s - f * (H * Wd);
    int hh = rem / Wd;
    int ww = rem - hh * Wd;
    int row = (i < 22) ? f : ((i < 43) ? hh : ww);
    float a = freqs[row * 64 + i];
    tabc[idx] = cosf(a);
    tabs[idx] = sinf(a);
  }
}

// ---------------- m97-structure GEMM (128x128) with XCD-locality remap ----------------
template <typename OUT>
__global__ __launch_bounds__(256, 2) void gemm_bt(const bf16* __restrict__ A, const bf16* __restrict__ B,
                                                  const float* __restrict__ bias, OUT* __restrict__ C,
                                                  int M, int N, int K, int gx) {
  __shared__ bf16 As[128 * 32], Bs[128 * 32];
  int t = threadIdx.x, l = t & 63, w = t >> 6;
  int lane15 = l & 15, lhi = l >> 4;
  int b = blockIdx.x;
  int xcd = b & 7, idx = b >> 3;
  int g = xcd * ((int)gridDim.x >> 3) + idx;
  int m0 = (g % gx) * 128, n0 = (g / gx) * 128;
  int wm = (w >> 1) * 64, wn = (w & 1) * 64;
  f32x4 zero = {0.f, 0.f, 0.f, 0.f};
  f32x4 acc[4][4];
#pragma unroll
  for (int i = 0; i < 4; ++i)
#pragma unroll
    for (int j = 0; j < 4; ++j) acc[i][j] = zero;

  int srow = t >> 2, scol = (t & 3) * 8;
  const bf16* gA0 = A + (size_t)(m0 + srow) * K + scol;
  const bf16* gA1 = A + (size_t)(m0 + 64 + srow) * K + scol;
  const bf16* gB0 = B + (size_t)(n0 + srow) * K + scol;
  const bf16* gB1 = B + (size_t)(n0 + 64 + srow) * K + scol;
  char* ldsA = (char*)As + (size_t)w * 1024;
  char* ldsB = (char*)Bs + (size_t)w * 1024;

  for (int kt = 0; kt < K; kt += 32) {
    gload_lds16(gA0 + kt, ldsA);
    gload_lds16(gA1 + kt, ldsA + 4096);
    gload_lds16(gB0 + kt, ldsB);
    gload_lds16(gB1 + kt, ldsB + 4096);
    __syncthreads();
    bf16x8 af[4], bfr[4];
#pragma unroll
    for (int i = 0; i < 4; ++i) {
      af[i]  = ld8(&As[(wm + i * 16 + lane15) * 32 + lhi * 8]);
      bfr[i] = ld8(&Bs[(wn + i * 16 + lane15) * 32 + lhi * 8]);
    }
#pragma unroll
    for (int i = 0; i < 4; ++i)
#pragma unroll
      for (int j = 0; j < 4; ++j)
        acc[i][j] = __builtin_amdgcn_mfma_f32_16x16x32_bf16(af[i], bfr[j], acc[i][j], 0, 0, 0);
    __syncthreads();
  }
#pragma unroll
  for (int i = 0; i < 4; ++i)
#pragma unroll
    for (int j = 0; j < 4; ++j) {
      int col = n0 + wn + j * 16 + lane15;
      float bb = bias[col];
#pragma unroll
      for (int r = 0; r < 4; ++r) {
        int row = m0 + wm + i * 16 + lhi * 4 + r;
        C[(size_t)row * N + col] = (OUT)(acc[i][j][r] + bb);
      }
    }
}

// ---------------- 64x128-tile GEMM for the out-projection (better occupancy) ----------------
// Same staging/fragment layout as gemm_bt, M-tile halved: 672 blocks (2.6/CU vs
// 1.3), acc = 8 f32x4 (32 VGPR) -> 4+ waves/SIMD. Wave w owns rows wm=w*16.
__global__ __launch_bounds__(256) void gemm_bt64(const bf16* __restrict__ A, const bf16* __restrict__ B,
                                                 const float* __restrict__ bias, float* __restrict__ C,
                                                 int M, int N, int K, int gx) {
  __shared__ bf16 As[64 * 32], Bs[128 * 32];
  int t = threadIdx.x, l = t & 63, w = t >> 6;
  int lane15 = l & 15, lhi = l >> 4;
  int b = blockIdx.x;
  int xcd = b & 7, idx = b >> 3;
  int g = xcd * ((int)gridDim.x >> 3) + idx;
  int m0 = (g % gx) * 64, n0 = (g / gx) * 128;
  int wm = w * 16;
  f32x4 zero = {0.f, 0.f, 0.f, 0.f};
  f32x4 acc[8];
#pragma unroll
  for (int j = 0; j < 8; ++j) acc[j] = zero;

  int srow = t >> 2, scol = (t & 3) * 8;
  const bf16* gA0 = A + (size_t)(m0 + srow) * K + scol;
  const bf16* gB0 = B + (size_t)(n0 + srow) * K + scol;
  const bf16* gB1 = B + (size_t)(n0 + 64 + srow) * K + scol;
  char* ldsA = (char*)As + (size_t)w * 1024;   // 4 waves x 1024B = 4096B = 64 rows
  char* ldsB = (char*)Bs + (size_t)w * 1024;

  for (int kt = 0; kt < K; kt += 32) {
    gload_lds16(gA0 + kt, ldsA);
    gload_lds16(gB0 + kt, ldsB);
    gload_lds16(gB1 + kt, ldsB + 4096);
    __syncthreads();
    bf16x8 af = ld8(&As[(wm + lane15) * 32 + lhi * 8]);
#pragma unroll
    for (int j = 0; j < 8; ++j) {
      bf16x8 bfr = ld8(&Bs[(j * 16 + lane15) * 32 + lhi * 8]);
      acc[j] = __builtin_amdgcn_mfma_f32_16x16x32_bf16(af, bfr, acc[j], 0, 0, 0);
    }
    __syncthreads();
  }
#pragma unroll
  for (int j = 0; j < 8; ++j) {
    int col = n0 + j * 16 + lane15;
    float bb = bias[col];
#pragma unroll
    for (int r = 0; r < 4; ++r) {
      int row = m0 + wm + lhi * 4 + r;
      C[(size_t)row * N + col] = acc[j][r] + bb;
    }
  }
}

// ---------------- fused: RMSNorm+RoPE (blocks 0..3583) | V-transpose (3584..4255) ----------------
__global__ __launch_bounds__(256) void postproc_v(const bf16* __restrict__ QKV,
    const float* __restrict__ gq, const float* __restrict__ gk,
    const float* __restrict__ tabc, const float* __restrict__ tabs,
    bf16* __restrict__ qb, bf16* __restrict__ kb, bf16* __restrict__ vT) {
  __shared__ bf16 tile[128][72];
  int b = blockIdx.x, t = threadIdx.x;
  if (b < 3584) {
    // ---- postproc path (192 active threads; all 256 hit the barrier) ----
    int s = b;
    __shared__ float red[2][3];
    float sq = 0.f, sk = 0.f;
    float qv[8], kv[8];
    int j0 = t * 8;
    if (t < 192) {
      const bf16* Qr = QKV + (size_t)s * 4608;
      bf16x8 qv8 = ld8(Qr + j0);
      bf16x8 kv8 = ld8(Qr + 1536 + j0);
#pragma unroll
      for (int j = 0; j < 8; ++j) {
        qv[j] = (float)qv8[j]; sq += qv[j] * qv[j];
        kv[j] = (float)kv8[j]; sk += kv[j] * kv[j];
      }
    }
#pragma unroll
    for (int off = 32; off > 0; off >>= 1) {
      sq += __shfl_down(sq, off);
      sk += __shfl_down(sk, off);
    }
    if ((t & 63) == 0 && t < 192) { red[0][t >> 6] = sq; red[1][t >> 6] = sk; }
    __syncthreads();
    if (t >= 192) return;
    float vq = red[0][0] + red[0][1] + red[0][2];
    float vk = red[1][0] + red[1][1] + red[1][2];
    float rq = 1.0f / sqrtf(vq * (1.0f / 1536.0f) + 1e-6f);
    float rk = 1.0f / sqrtf(vk * (1.0f / 1536.0f) + 1e-6f);
    rq *= 0.08838834764831845f;   // fold attention scale into Q
    int i0 = (j0 >> 1) & 63;
    float4 cq = *(const float4*)(tabc + s * 64 + i0);
    float4 sq4 = *(const float4*)(tabs + s * 64 + i0);
    float cc[4] = {cq.x, cq.y, cq.z, cq.w};
    float sn[4] = {sq4.x, sq4.y, sq4.z, sq4.w};
    float4 g0 = *(const float4*)(gq + j0), g1 = *(const float4*)(gq + j0 + 4);
    float4 k0 = *(const float4*)(gk + j0), k1 = *(const float4*)(gk + j0 + 4);
    float gqa[8] = {g0.x, g0.y, g0.z, g0.w, g1.x, g1.y, g1.z, g1.w};
    float gka[8] = {k0.x, k0.y, k0.z, k0.w, k1.x, k1.y, k1.z, k1.w};
    int d0 = j0 & 127, h = j0 >> 7;
    bf16x8 qo, ko;
#pragma unroll
    for (int p = 0; p < 4; ++p) {
      float a = qv[2 * p] * rq * gqa[2 * p];
      float b2 = qv[2 * p + 1] * rq * gqa[2 * p + 1];
      qo[2 * p] = (bf16)(a * cc[p] - b2 * sn[p]);
      qo[2 * p + 1] = (bf16)(a * sn[p] + b2 * cc[p]);
      float ak = kv[2 * p] * rk * gka[2 * p];
      float bk2 = kv[2 * p + 1] * rk * gka[2 * p + 1];
      ko[2 * p] = (bf16)(ak * cc[p] - bk2 * sn[p]);
      ko[2 * p + 1] = (bf16)(ak * sn[p] + bk2 * cc[p]);
    }
    *(bf16x8*)(qb + (((size_t)h * 3584 + s) << 7) + d0) = qo;
    int sw = (s & 7) << 3;
    *(bf16x8*)(kb + (((size_t)(h * 56 + (s >> 6)) * 64 + (s & 63)) << 7) + (d0 ^ sw)) = ko;
  } else {
    // ---- transpose_v path: V -> vT image [h][tile][drow=128][slot^((drow&7)<<3)] ----
    int idx = b - 3584;           // 672 blocks
    int xt = idx % 56, h = idx / 56;
    int s0 = xt * 64;
    int r = t >> 2, c0 = (t & 3) * 32;
    const bf16* src = QKV + (size_t)(s0 + r) * 4608 + 3072 + h * 128 + c0;
#pragma unroll
    for (int q = 0; q < 4; ++q) {
      bf16x8 v = ld8(src + q * 8);
#pragma unroll
      for (int j = 0; j < 8; ++j) tile[c0 + q * 8 + j][r] = v[j];
    }
    __syncthreads();
    int d = t >> 1, spHalf = t & 1;
    int sw = (d & 7) << 3;
    bf16* dstBase = vT + ((size_t)(h * 56 + xt) * 128 + d) * 64;
#pragma unroll
    for (int q = 0; q < 4; ++q) {
      int mm = spHalf * 4 + q;
      int sA = 32 * (mm >> 2) + 16 * (mm & 1) + 4 * ((mm >> 1) & 1);
      bf16x4 lo, hi;
#pragma unroll
      for (int j = 0; j < 4; ++j) {
        lo[j] = tile[d][spHalf * 32 + q * 8 + j];
        hi[j] = tile[d][spHalf * 32 + q * 8 + 4 + j];
      }
      int slo = sA ^ sw;
      *(bf16x4*)(dstBase + slo) = lo;
      *(bf16x4*)(dstBase + (slo ^ 8)) = hi;
    }
  }
}

// ---------------- flash attention: R14-EXACT (130.2 us verified optimum) ----------------
// Single 32KB buffer, 2 barriers/tile, zero-register gload_lds staging from
// pre-swizzled images, XCD decode, e-domain softmax (exp2f = slow libm, R13),
// defer-max THR=8, no setprio (R15: priority inversion, -5%).
// launch_bounds min-waves MUST stay 2 (R4: (256,3) spilled the accumulators).
__global__ __launch_bounds__(256, 2) void flash_attn(
    const bf16* __restrict__ qb, const bf16* __restrict__ kb, const bf16* __restrict__ vT,
    const int* __restrict__ sl, bf16* __restrict__ po0, bf16* __restrict__ po1,
    bf16* __restrict__ po2, bf16* __restrict__ po3, float* __restrict__ ml) {
  const int L = 3584;
  __shared__ bf16 Ks[64 * 128];
  __shared__ bf16 Vs[128 * 64];
  int t = threadIdx.x, l = t & 63, w = t >> 6;
  int lane15 = l & 15, lhi = l >> 4;
  int grp48 = l & 48;
  int b = blockIdx.x;
  int xcd = b & 7, k_ = b >> 3;
  int pg = k_ / 28, x = k_ - pg * 28;
  int p = pg * 8 + xcd;
  int h = p % 12, z = p / 12;
  int qw = x * 128 + w * 32;
  int seqlen = sl[0];
  bf16* po = (z == 0) ? po0 : (z == 1) ? po1 : (z == 2) ? po2 : po3;
  float* mlz = ml + (size_t)z * 12 * L * 2;

  bf16x8 aq[2][4];
#pragma unroll
  for (int qf = 0; qf < 2; ++qf)
#pragma unroll
    for (int kc = 0; kc < 4; ++kc)
      aq[qf][kc] = ld8(qb + (((size_t)h * L + qw + qf * 16 + lane15) << 7) + kc * 32 + lhi * 8);

  f32x4 zero = {0.f, 0.f, 0.f, 0.f};
  f32x4 out[2][8];
  float m2[2] = {-1e30f, -1e30f}, ls2[2] = {0.f, 0.f};
#pragma unroll
  for (int qf = 0; qf < 2; ++qf)
#pragma unroll
    for (int df = 0; df < 8; ++df) out[qf][df] = zero;

  int nt = (seqlen + 63) >> 6;
  if (nt > 56) nt = 56;
  int t0 = z * 14, t1 = t0 + 14;
  if (t0 > nt) t0 = nt;
  if (t1 > nt) t1 = nt;

  int src_off = w * 1024 + l * 16;
  char* ksd = (char*)Ks + w * 1024;
  char* vsd = (char*)Vs + w * 1024;

  for (int ti = t0; ti < t1; ++ti) {
    int kv0 = ti * 64;
    __syncthreads();
    {
      const char* kimg = (const char*)kb + ((size_t)(h * 56) + ti) * 16384;
      const char* vimg = (const char*)vT + ((size_t)(h * 56) + ti) * 16384;
#pragma unroll
      for (int pp = 0; pp < 4; ++pp) {
        gload_lds16(kimg + pp * 4096 + src_off, ksd + pp * 4096);
        gload_lds16(vimg + pp * 4096 + src_off, vsd + pp * 4096);
      }
    }
    __syncthreads();

    f32x4 sc[2][4];
#pragma unroll
    for (int qf = 0; qf < 2; ++qf)
#pragma unroll
      for (int a = 0; a < 4; ++a) sc[qf][a] = zero;
#pragma unroll
    for (int a = 0; a < 4; ++a) {
      int rk = a * 16 + lane15;
      const char* krow = (const char*)Ks + rk * 256;
      int swz = (rk & 7) << 4;
#pragma unroll
      for (int kc = 0; kc < 4; ++kc) {
        bf16x8 bk_ = ld8((const bf16*)(krow + ((kc * 64 + lhi * 16) ^ swz)));
        sc[0][a] = __builtin_amdgcn_mfma_f32_16x16x32_bf16(bk_, aq[0][kc], sc[0][a], 0, 0, 0);
        sc[1][a] = __builtin_amdgcn_mfma_f32_16x16x32_bf16(bk_, aq[1][kc], sc[1][a], 0, 0, 0);
      }
    }

    bool full = (kv0 + 64 <= seqlen);
    bf16x8 ap[2][2];
#pragma unroll
    for (int qf = 0; qf < 2; ++qf) {
      float tm = -1e30f;
#pragma unroll
      for (int a = 0; a < 4; ++a)
#pragma unroll
        for (int r = 0; r < 4; ++r) {
          float s = sc[qf][a][r];
          if (!full) {
            int col = kv0 + a * 16 + lhi * 4 + r;
            s = (col < seqlen) ? s : -1e30f;
            sc[qf][a][r] = s;
          }
          tm = fmaxf(tm, s);
        }
      tm = fmaxf(tm, __shfl_xor(tm, 16));
      tm = fmaxf(tm, __shfl_xor(tm, 32));
      if (!__all(tm <= m2[qf] + 8.0f)) {
        float nm = fmaxf(m2[qf], tm);
        float f = __expf(m2[qf] - nm);
        m2[qf] = nm;
        ls2[qf] *= f;
#pragma unroll
        for (int r = 0; r < 4; ++r) {
          float fr = __shfl(f, grp48 | (lhi * 4 + r));
#pragma unroll
          for (int df = 0; df < 8; ++df) out[qf][df][r] *= fr;
        }
      }
      float psum = 0.f;
#pragma unroll
      for (int a = 0; a < 4; ++a)
#pragma unroll
        for (int r = 0; r < 4; ++r) {
          float pv = __expf(sc[qf][a][r] - m2[qf]);
          sc[qf][a][r] = pv;
          psum += pv;
        }
      psum += __shfl_xor(psum, 16);
      psum += __shfl_xor(psum, 32);
      ls2[qf] += psum;
#pragma unroll
      for (int c = 0; c < 2; ++c) {
        bf16x8 f8;
#pragma unroll
        for (int r = 0; r < 4; ++r) {
          f8[r] = (bf16)sc[qf][2 * c][r];
          f8[r + 4] = (bf16)sc[qf][2 * c + 1][r];
        }
        ap[qf][c] = f8;
      }
    }

#pragma unroll
    for (int df = 0; df < 8; ++df) {
      int rd = df * 16 + lane15;
      const char* vrow2 = (const char*)Vs + rd * 128;
      int swz = (rd & 7) << 4;
#pragma unroll
      for (int c = 0; c < 2; ++c) {
        bf16x8 bv_ = ld8((const bf16*)(vrow2 + ((c * 64 + lhi * 16) ^ swz)));
        out[0][df] = __builtin_amdgcn_mfma_f32_16x16x32_bf16(ap[0][c], bv_, out[0][df], 0, 0, 0);
        out[1][df] = __builtin_amdgcn_mfma_f32_16x16x32_bf16(ap[1][c], bv_, out[1][df], 0, 0, 0);
      }
    }
  }

#pragma unroll
  for (int qf = 0; qf < 2; ++qf) {
#pragma unroll
    for (int r = 0; r < 4; ++r) {
      int row = qw + qf * 16 + lhi * 4 + r;
      size_t rbase = ((size_t)h * L + row) << 7;
#pragma unroll
      for (int df = 0; df < 8; ++df)
        po[rbase + df * 16 + lane15] = (bf16)out[qf][df][r];
    }
    if (lhi == 0) {
      int row = qw + qf * 16 + lane15;
      mlz[(((size_t)h * L + row) << 1)] = m2[qf];
      mlz[(((size_t)h * L + row) << 1) + 1] = ls2[qf];
    }
  }
}

// ---------------- combine the four KV-split slices — bf16x8 vectorized ----------------
__global__ __launch_bounds__(256) void combine4(
    const bf16* __restrict__ po0, const bf16* __restrict__ po1,
    const bf16* __restrict__ po2, const bf16* __restrict__ po3,
    const float* __restrict__ ml, bf16* __restrict__ attn) {
  const int L = 3584;
  int row = blockIdx.x * 16 + (threadIdx.x >> 4);
  int c0 = (threadIdx.x & 15) * 8;
  const size_t mls = (size_t)12 * L * 2;
  float m0 = ml[row * 2],           l0 = ml[row * 2 + 1];
  float m1 = ml[mls + row * 2],     l1 = ml[mls + row * 2 + 1];
  float m2 = ml[2 * mls + row * 2], l2 = ml[2 * mls + row * 2 + 1];
  float m3 = ml[3 * mls + row * 2], l3 = ml[3 * mls + row * 2 + 1];
  float M = fmaxf(fmaxf(m0, m1), fmaxf(m2, m3));
  float w0 = __expf(m0 - M), w1 = __expf(m1 - M);
  float w2 = __expf(m2 - M), w3 = __expf(m3 - M);
  float inv = 1.0f / fmaxf(w0 * l0 + w1 * l1 + w2 * l2 + w3 * l3, 1e-30f);
  bf16x8 a = ld8(po0 + (size_t)row * 128 + c0);
  bf16x8 b = ld8(po1 + (size_t)row * 128 + c0);
  bf16x8 c = ld8(po2 + (size_t)row * 128 + c0);
  bf16x8 d = ld8(po3 + (size_t)row * 128 + c0);
  int h = row / L, s = row % L;
  bf16x8 o;
#pragma unroll
  for (int j = 0; j < 8; ++j)
    o[j] = (bf16)((w0 * (float)a[j] + w1 * (float)b[j] + w2 * (float)c[j] + w3 * (float)d[j]) * inv);
  *(bf16x8*)(attn + (size_t)s * 1536 + h * 128 + c0) = o;
}

// ---------------- launcher ----------------
extern "C" void kernel_launch(void* const* d_in, const int* in_sizes, int n_in,
                              void* d_out, int out_size, void* d_ws, size_t ws_size,
                              hipStream_t stream) {
  const float* x = (const float*)d_in[0];
  const int* seq_lens = (const int*)d_in[1];
  const int* grid_sizes = (const int*)d_in[2];
  const float* freqs = (const float*)d_in[3];
  const float* Wq = (const float*)d_in[4];
  const float* bq = (const float*)d_in[5];
  const float* Wk = (const float*)d_in[6];
  const float* bk = (const float*)d_in[7];
  const float* Wv = (const float*)d_in[8];
  const float* bv = (const float*)d_in[9];
  const float* Wo = (const float*)d_in[10];
  const float* bo = (const float*)d_in[11];
  const float* gq = (const float*)d_in[12];
  const float* gk = (const float*)d_in[13];

  char* ws = (char*)d_ws;
  bf16* x_bf = (bf16*)(ws + 0);             // 11,010,048  (dead after QKV GEMM)
  bf16* wqkvt = (bf16*)(ws + 11010048);     // 14,155,776  (dead after QKV GEMM)
  bf16* wot = (bf16*)(ws + 25165824);       //  4,718,592  (live until final GEMM)
  float* bqkv = (float*)(ws + 29884416);    //     18,432
  bf16* QKV = (bf16*)(ws + 29902848);       // 33,030,144  (dead after postproc_v)
  bf16* qb = (bf16*)(ws + 62932992);        // 11,010,048
  bf16* kb = (bf16*)(ws + 73943040);        // 11,010,048  (K image)
  bf16* vT = (bf16*)(ws + 84953088);        // 11,010,048  (V image)
  float* tabc = (float*)(ws + 95963136);    //    917,504  (dead after postproc_v)
  float* tabs = (float*)(ws + 96880640);    //    917,504
  // overlays for the flash phase (underlying buffers dead by then); bf16 partials
  bf16* po0 = (bf16*)(ws + 29902848);       // over QKV head
  bf16* attn = (bf16*)(ws + 51922944);      // over QKV tail
  bf16* po1 = (bf16*)(ws + 0);              // over x_bf
  bf16* po2 = (bf16*)(ws + 11010048);       // over wqkvt
  float* ml  = (float*)(ws + 95963136);     // over tabc+tabs
  bf16* po3 = (bf16*)(ws + 97798144);       // tail (ends 108,808,192)

  prologue<<<5888, 256, 0, stream>>>(x, Wq, Wk, Wv, Wo, freqs, grid_sizes, bq, bk, bv,
                                     x_bf, wqkvt, wot, tabc, tabs, bqkv);
  gemm_bt<bf16><<<1008, 256, 0, stream>>>(x_bf, wqkvt, bqkv, QKV, 3584, 4608, 1536, 28);
  postproc_v<<<4256, 256, 0, stream>>>(QKV, gq, gk, tabc, tabs, qb, kb, vT);
  flash_attn<<<1344, 256, 0, stream>>>(qb, kb, vT, seq_lens, po0, po1, po2, po3, ml);
  combine4<<<2688, 256, 0, stream>>>(po0, po1, po2, po3, ml, attn);
  gemm_bt64<<<672, 256, 0, stream>>>(attn, wot, bo, (float*)d_out, 3584, 1536, 1536, 56);
}